// Round 1
// baseline (1078.626 us; speedup 1.0000x reference)
//
#include <hip/hip_runtime.h>
#include <math.h>

#pragma clang fp contract(off)

#define NCLS 80
#define NTOT 3800
#define NBINS 131072
#define CAND_CAP 4096
#define NMS_CAP 1024
#define TOTAL_E 4264000
// element cumsums (hw*80): p3=3200000 p4=800000 p5=200000 p6=51200 p7=12800
#define C1 3200000
#define C2 4000000
#define C3 4200000
#define C4 4251200

struct Params {
  const float *cls0,*cls1,*cls2,*cls3,*cls4;
  const float *ctn0,*ctn1,*ctn2,*ctn3,*ctn4;
  const float *box0,*box1,*box2,*box3,*box4;
  const int* img;
  unsigned* hist;            // 5*NBINS
  unsigned* cnt;             // 5
  unsigned* thr;             // 5
  unsigned long long* cand;  // 5*CAND_CAP
  unsigned* slot_bits;       // NTOT
  unsigned* slot_label;      // NTOT
  float* slot_box;           // NTOT*4 (raw boxes)
  float* out;                // 26600 floats
};

// --- score: emulate f32 pipeline with correctly-rounded expf (f64 exp -> f32)
__device__ __forceinline__ float sigmoid_ref(float x) {
  float e = (float)exp(-(double)x);   // ~correctly-rounded float exp
  return 1.0f / (1.0f + e);           // f32 add, f32 div (IEEE exact rounding)
}
__device__ __forceinline__ float score_ref(float c, float t) {
  return sqrtf(sigmoid_ref(c) * sigmoid_ref(t));
}

// --- IoU exactly as reference (on class-offset coords), contract off file-wide
__device__ __forceinline__ float iou_ref(float ax1,float ay1,float ax2,float ay2,
                                         float bx1,float by1,float bx2,float by2) {
  float areaA = fmaxf(ax2-ax1,0.0f) * fmaxf(ay2-ay1,0.0f);
  float areaB = fmaxf(bx2-bx1,0.0f) * fmaxf(by2-by1,0.0f);
  float ix1 = fmaxf(ax1,bx1), iy1 = fmaxf(ay1,by1);
  float ix2 = fminf(ax2,bx2), iy2 = fminf(ay2,by2);
  float inter = fmaxf(ix2-ix1,0.0f) * fmaxf(iy2-iy1,0.0f);
  float uni = areaA + areaB - inter;
  return inter / fmaxf(uni, 1e-9f);
}

__device__ __forceinline__ void decode(int idx, const Params& p,
                                       int& l, int& f, const float*& cls, const float*& ctn) {
  if (idx < C1)      { l=0; f=idx;     cls=p.cls0; ctn=p.ctn0; }
  else if (idx < C2) { l=1; f=idx-C1;  cls=p.cls1; ctn=p.ctn1; }
  else if (idx < C3) { l=2; f=idx-C2;  cls=p.cls2; ctn=p.ctn2; }
  else if (idx < C4) { l=3; f=idx-C3;  cls=p.cls3; ctn=p.ctn3; }
  else               { l=4; f=idx-C4;  cls=p.cls4; ctn=p.ctn4; }
}

__global__ __launch_bounds__(256) void k_zero(unsigned* hist) {
  int i = blockIdx.x*256 + threadIdx.x;
  if (i < 5*NBINS) hist[i] = 0u;
}

__global__ __launch_bounds__(256) void k_hist(Params p) {
  int idx = blockIdx.x*256 + threadIdx.x;
  if (idx >= TOTAL_E) return;
  int l, f; const float *cls, *ctn;
  decode(idx, p, l, f, cls, ctn);
  float s = score_ref(cls[f], ctn[f / NCLS]);
  atomicAdd(&p.hist[l*NBINS + (__float_as_uint(s) >> 13)], 1u);
}

__global__ __launch_bounds__(256) void k_thresh(Params p) {
  int l = blockIdx.x, tid = threadIdx.x;
  __shared__ unsigned csum[256];
  const unsigned* h = p.hist + l*NBINS;
  const int KL[5] = {1000,1000,1000,640,160};
  unsigned s = 0;
  for (int i = 0; i < 512; ++i) s += h[tid*512 + i];
  csum[tid] = s;
  __syncthreads();
  if (tid == 0) {
    unsigned k = (unsigned)KL[l];
    unsigned cum = 0; int chunk = 255;
    for (; chunk > 0; --chunk) {
      if (cum + csum[chunk] >= k) break;
      cum += csum[chunk];
    }
    unsigned tb = 0;
    for (int i = 511; i >= 0; --i) {
      int bin = chunk*512 + i;
      cum += h[bin];
      if (cum >= k) { tb = (unsigned)bin; break; }
    }
    p.thr[l] = tb << 13;
    p.cnt[l] = 0u;   // reset gather counter for k_gather
  }
}

__global__ __launch_bounds__(256) void k_gather(Params p) {
  int idx = blockIdx.x*256 + threadIdx.x;
  if (idx >= TOTAL_E) return;
  int l, f; const float *cls, *ctn;
  decode(idx, p, l, f, cls, ctn);
  float s = score_ref(cls[f], ctn[f / NCLS]);
  unsigned bits = __float_as_uint(s);
  if (bits >= p.thr[l]) {
    unsigned pos = atomicAdd(&p.cnt[l], 1u);
    if (pos < CAND_CAP)
      p.cand[l*CAND_CAP + pos] =
        ((unsigned long long)bits << 32) | (unsigned long long)(0xFFFFFFFFu - (unsigned)f);
  }
}

__device__ __forceinline__ void bitonic_asc(unsigned long long* key, int n, int tid, int nthr) {
  for (int k = 2; k <= n; k <<= 1) {
    for (int j = k >> 1; j > 0; j >>= 1) {
      for (int i = tid; i < n; i += nthr) {
        int ixj = i ^ j;
        if (ixj > i) {
          unsigned long long a = key[i], b = key[ixj];
          bool up = ((i & k) == 0);
          if ((a > b) == up) { key[i] = b; key[ixj] = a; }
        }
      }
      __syncthreads();
    }
  }
}

__global__ __launch_bounds__(256) void k_sort_out(Params p) {
  int l = blockIdx.x, tid = threadIdx.x;
  __shared__ unsigned long long key[CAND_CAP];
  unsigned m = p.cnt[l]; if (m > CAND_CAP) m = CAND_CAP;
  const unsigned long long* cd = p.cand + l*CAND_CAP;
  for (int i = tid; i < CAND_CAP; i += 256) key[i] = (i < (int)m) ? cd[i] : 0ULL;
  __syncthreads();
  bitonic_asc(key, CAND_CAP, tid, 256);
  const int KL[5] = {1000,1000,1000,640,160};
  const int OB[5] = {0,1000,2000,3000,3640};
  const float* box = (l==0)?p.box0:(l==1)?p.box1:(l==2)?p.box2:(l==3)?p.box3:p.box4;
  int kL = KL[l], base = OB[l];
  float img = (float)(*p.img);
  for (int r = tid; r < kL; r += 256) {
    unsigned long long kk = key[CAND_CAP - 1 - r];
    int g = base + r;
    if (kk == 0ULL) {  // defensive: should not happen (m >= kL guaranteed)
      p.out[NTOT + g] = 0.0f;
      for (int j = 0; j < 4; ++j) { p.out[2*NTOT + g*4 + j] = 0.0f; p.slot_box[g*4+j] = 0.0f; }
      p.slot_bits[g] = 0u; p.slot_label[g] = 0u;
      continue;
    }
    unsigned bits = (unsigned)(kk >> 32);
    unsigned fi = 0xFFFFFFFFu - (unsigned)(kk & 0xFFFFFFFFu);
    unsigned lab = fi % NCLS;
    unsigned a = fi / NCLS;
    p.out[NTOT + g] = (float)lab;
    for (int j = 0; j < 4; ++j) {
      float b = box[a*4 + j];
      float nb = b / img;
      nb = fminf(fmaxf(nb, 0.0f), 1.0f);
      p.out[2*NTOT + g*4 + j] = nb;
      p.slot_box[g*4 + j] = b;
    }
    p.slot_bits[g] = bits;
    p.slot_label[g] = lab;
  }
}

__global__ __launch_bounds__(64) void k_nms(Params p) {
  int c = blockIdx.x, tid = threadIdx.x;
  __shared__ unsigned mcnt;
  __shared__ unsigned long long key[NMS_CAP];
  __shared__ float bx[NMS_CAP*4];
  __shared__ int keep[NMS_CAP];
  if (tid == 0) mcnt = 0u;
  __syncthreads();
  for (int g = tid; g < NTOT; g += 64) {
    if (p.slot_label[g] == (unsigned)c) {
      unsigned pos = atomicAdd(&mcnt, 1u);
      if (pos < NMS_CAP)
        key[pos] = ((unsigned long long)p.slot_bits[g] << 32)
                 | (unsigned long long)(0xFFFFFFFFu - (unsigned)g);
    }
  }
  __syncthreads();
  int m = (mcnt < NMS_CAP) ? (int)mcnt : NMS_CAP;
  if (m == 0) return;
  int pw = 1; while (pw < m) pw <<= 1;
  for (int i = m + tid; i < pw; i += 64) key[i] = 0ULL;
  __syncthreads();
  bitonic_asc(key, pw, tid, 64);
  float off = 2.0f * (float)c;   // class offset, rounded as ref does
  for (int j = tid; j < m; j += 64) {
    unsigned long long kk = key[pw - 1 - j];
    unsigned g = 0xFFFFFFFFu - (unsigned)(kk & 0xFFFFFFFFu);
    for (int q = 0; q < 4; ++q) bx[j*4+q] = p.slot_box[g*4+q] + off;
    float s = __uint_as_float((unsigned)(kk >> 32));
    keep[j] = (s > 0.05f) ? 1 : 0;
  }
  __syncthreads();
  for (int i = 0; i + 1 < m; ++i) {
    if (keep[i]) {
      float ax1 = bx[i*4+0], ay1 = bx[i*4+1], ax2 = bx[i*4+2], ay2 = bx[i*4+3];
      for (int j = i + 1 + tid; j < m; j += 64) {
        if (keep[j]) {
          if (iou_ref(ax1,ay1,ax2,ay2, bx[j*4+0],bx[j*4+1],bx[j*4+2],bx[j*4+3]) > 0.6f)
            keep[j] = 0;
        }
      }
    }
    __syncthreads();
  }
  for (int j = tid; j < m; j += 64) {
    unsigned long long kk = key[pw - 1 - j];
    unsigned g = 0xFFFFFFFFu - (unsigned)(kk & 0xFFFFFFFFu);
    float s = __uint_as_float((unsigned)(kk >> 32));
    int kp = keep[j];
    p.out[g] = kp ? s : 0.0f;             // scores * keep (keep ⊆ valid)
    p.out[6*NTOT + g] = kp ? 1.0f : 0.0f; // keep flag at offset 22800
  }
}

extern "C" void kernel_launch(void* const* d_in, const int* in_sizes, int n_in,
                              void* d_out, int out_size, void* d_ws, size_t ws_size,
                              hipStream_t stream) {
  Params p;
  p.cls0 = (const float*)d_in[0];  p.ctn0 = (const float*)d_in[1];  p.box0 = (const float*)d_in[2];
  p.cls1 = (const float*)d_in[3];  p.ctn1 = (const float*)d_in[4];  p.box1 = (const float*)d_in[5];
  p.cls2 = (const float*)d_in[6];  p.ctn2 = (const float*)d_in[7];  p.box2 = (const float*)d_in[8];
  p.cls3 = (const float*)d_in[9];  p.ctn3 = (const float*)d_in[10]; p.box3 = (const float*)d_in[11];
  p.cls4 = (const float*)d_in[12]; p.ctn4 = (const float*)d_in[13]; p.box4 = (const float*)d_in[14];
  p.img  = (const int*)d_in[15];

  char* w = (char*)d_ws;
  p.cand = (unsigned long long*)w; w += (size_t)5*CAND_CAP*8;   // 163840 B
  p.hist = (unsigned*)w;           w += (size_t)5*NBINS*4;      // 2621440 B
  p.cnt  = (unsigned*)w;           w += 5*4;
  p.thr  = (unsigned*)w;           w += 5*4;
  p.slot_bits  = (unsigned*)w;     w += NTOT*4;
  p.slot_label = (unsigned*)w;     w += NTOT*4;
  p.slot_box   = (float*)w;        w += NTOT*4*4;
  p.out = (float*)d_out;

  hipLaunchKernelGGL(k_zero,     dim3((5*NBINS+255)/256), dim3(256), 0, stream, p.hist);
  hipLaunchKernelGGL(k_hist,     dim3((TOTAL_E+255)/256), dim3(256), 0, stream, p);
  hipLaunchKernelGGL(k_thresh,   dim3(5),                 dim3(256), 0, stream, p);
  hipLaunchKernelGGL(k_gather,   dim3((TOTAL_E+255)/256), dim3(256), 0, stream, p);
  hipLaunchKernelGGL(k_sort_out, dim3(5),                 dim3(256), 0, stream, p);
  hipLaunchKernelGGL(k_nms,      dim3(80),                dim3(64),  0, stream, p);
}

// Round 2
// 493.168 us; speedup vs baseline: 2.1871x; 2.1871x over previous
//
#include <hip/hip_runtime.h>
#include <math.h>

#pragma clang fp contract(off)

#define NCLS 80
#define NTOT 3800
#define CAND_CAP 4096
#define NMS_CAP 1024
#define TOTAL_E 4264000
#define C1 3200000
#define C2 4000000
#define C3 4200000
#define C4 4251200
// histogram over score float-bits in [0.25, 1.0): 1024 bins of 2^14 ULP
#define BIN_LO 0x3E800000u
#define NB 1024
#define BSHIFT 14
// per-level chunking for the LDS-hist pass
#define EPB 8192
#define NBLK 523

__constant__ int d_BSTART[6] = {0, 391, 489, 514, 521, 523};
__constant__ int d_EL[5] = {3200000, 800000, 200000, 51200, 12800};

struct Params {
  const float *cls0,*cls1,*cls2,*cls3,*cls4;
  const float *ctn0,*ctn1,*ctn2,*ctn3,*ctn4;
  const float *box0,*box1,*box2,*box3,*box4;
  const int* img;
  unsigned* blockhist;       // NBLK * NB
  unsigned* cnt;             // 5
  unsigned* thr;             // 5
  unsigned long long* cand;  // 5*CAND_CAP
  unsigned* slot_bits;       // NTOT
  unsigned* slot_label;      // NTOT
  float* slot_box;           // NTOT*4 (raw boxes)
  float* out;                // 26600 floats
};

// --- score: emulate f32 pipeline with correctly-rounded expf (f64 exp -> f32)
__device__ __forceinline__ float sigmoid_ref(float x) {
  float e = (float)exp(-(double)x);
  return 1.0f / (1.0f + e);
}
__device__ __forceinline__ float score_ref(float c, float t) {
  return sqrtf(sigmoid_ref(c) * sigmoid_ref(t));
}

__device__ __forceinline__ float iou_ref(float ax1,float ay1,float ax2,float ay2,
                                         float bx1,float by1,float bx2,float by2) {
  float areaA = fmaxf(ax2-ax1,0.0f) * fmaxf(ay2-ay1,0.0f);
  float areaB = fmaxf(bx2-bx1,0.0f) * fmaxf(by2-by1,0.0f);
  float ix1 = fmaxf(ax1,bx1), iy1 = fmaxf(ay1,by1);
  float ix2 = fminf(ax2,bx2), iy2 = fminf(ay2,by2);
  float inter = fmaxf(ix2-ix1,0.0f) * fmaxf(iy2-iy1,0.0f);
  float uni = areaA + areaB - inter;
  return inter / fmaxf(uni, 1e-9f);
}

__device__ __forceinline__ void decode(int idx, const Params& p,
                                       int& l, int& f, const float*& cls, const float*& ctn) {
  if (idx < C1)      { l=0; f=idx;     cls=p.cls0; ctn=p.ctn0; }
  else if (idx < C2) { l=1; f=idx-C1;  cls=p.cls1; ctn=p.ctn1; }
  else if (idx < C3) { l=2; f=idx-C2;  cls=p.cls2; ctn=p.ctn2; }
  else if (idx < C4) { l=3; f=idx-C3;  cls=p.cls3; ctn=p.ctn3; }
  else               { l=4; f=idx-C4;  cls=p.cls4; ctn=p.ctn4; }
}

// Pass 1: per-block LDS histogram -> private global array (no global atomics)
__global__ __launch_bounds__(256) void k_hist(Params p) {
  int b = blockIdx.x, tid = threadIdx.x;
  __shared__ unsigned h[NB];
  for (int i = tid; i < NB; i += 256) h[i] = 0u;
  __syncthreads();
  int l = 0;
  while (b >= d_BSTART[l+1]) ++l;
  int cb = b - d_BSTART[l];
  int e0 = cb * EPB;
  int cnt = d_EL[l] - e0; if (cnt > EPB) cnt = EPB;
  const float* cls = (l==0)?p.cls0:(l==1)?p.cls1:(l==2)?p.cls2:(l==3)?p.cls3:p.cls4;
  const float* ctn = (l==0)?p.ctn0:(l==1)?p.ctn1:(l==2)?p.ctn2:(l==3)?p.ctn3:p.ctn4;
  for (int i = tid; i < cnt; i += 256) {
    int f = e0 + i;
    float s = score_ref(cls[f], ctn[f / NCLS]);
    unsigned bits = __float_as_uint(s);
    if (bits >= BIN_LO) {
      unsigned bin = (bits - BIN_LO) >> BSHIFT;   // 0..1023
      atomicAdd(&h[bin], 1u);                      // LDS atomic
    }
  }
  __syncthreads();
  unsigned* out = p.blockhist + (size_t)b * NB;
  for (int i = tid; i < NB; i += 256) out[i] = h[i];
}

// Reduce block hists per level, find k-th threshold bin
__global__ __launch_bounds__(256) void k_thresh(Params p) {
  int l = blockIdx.x, tid = threadIdx.x;
  __shared__ unsigned tot[NB];
  __shared__ unsigned csum[256];
  int b0 = d_BSTART[l], b1 = d_BSTART[l+1];
  for (int j = 0; j < NB/256; ++j) {
    int bin = tid + 256*j;
    unsigned s = 0;
    for (int b = b0; b < b1; ++b) s += p.blockhist[(size_t)b * NB + bin];
    tot[bin] = s;
  }
  __syncthreads();
  {
    unsigned s = 0;
    for (int j = 0; j < 4; ++j) s += tot[tid*4 + j];
    csum[tid] = s;
  }
  __syncthreads();
  if (tid == 0) {
    const int KL[5] = {1000,1000,1000,640,160};
    unsigned k = (unsigned)KL[l];
    unsigned cum = 0; int chunk = 255;
    for (; chunk > 0; --chunk) {
      if (cum + csum[chunk] >= k) break;
      cum += csum[chunk];
    }
    unsigned t = BIN_LO;  // fallback (statistically unreachable)
    unsigned c2 = cum;
    for (int i = 3; i >= 0; --i) {
      int bin = chunk*4 + i;
      c2 += tot[bin];
      if (c2 >= k) { t = BIN_LO + ((unsigned)bin << BSHIFT); break; }
    }
    p.thr[l] = t;
    p.cnt[l] = 0u;
  }
}

// Pass 2: gather candidates >= threshold (few thousand atomics total)
__global__ __launch_bounds__(256) void k_gather(Params p) {
  int idx = blockIdx.x*256 + threadIdx.x;
  if (idx >= TOTAL_E) return;
  int l, f; const float *cls, *ctn;
  decode(idx, p, l, f, cls, ctn);
  float s = score_ref(cls[f], ctn[f / NCLS]);
  unsigned bits = __float_as_uint(s);
  if (bits >= p.thr[l]) {
    unsigned pos = atomicAdd(&p.cnt[l], 1u);
    if (pos < CAND_CAP)
      p.cand[l*CAND_CAP + pos] =
        ((unsigned long long)bits << 32) | (unsigned long long)(0xFFFFFFFFu - (unsigned)f);
  }
}

// Rank-sort (O(m^2) broadcast compares) + emit labels/normalized boxes
__global__ __launch_bounds__(1024) void k_sort_out(Params p) {
  int l = blockIdx.x, tid = threadIdx.x;
  __shared__ unsigned long long key[CAND_CAP];
  unsigned mc = p.cnt[l];
  int m = (mc < CAND_CAP) ? (int)mc : CAND_CAP;
  const unsigned long long* cd = p.cand + (size_t)l*CAND_CAP;
  for (int i = tid; i < m; i += 1024) key[i] = cd[i];
  __syncthreads();
  const int KL[5] = {1000,1000,1000,640,160};
  const int OB[5] = {0,1000,2000,3000,3640};
  const float* box = (l==0)?p.box0:(l==1)?p.box1:(l==2)?p.box2:(l==3)?p.box3:p.box4;
  int kL = KL[l], base = OB[l];
  float img = (float)(*p.img);
  for (int i = tid; i < m; i += 1024) {
    unsigned long long mine = key[i];
    int rank = 0;
    for (int j = 0; j < m; ++j) rank += (key[j] > mine) ? 1 : 0;
    if (rank < kL) {
      int g = base + rank;
      unsigned bits = (unsigned)(mine >> 32);
      unsigned fi = 0xFFFFFFFFu - (unsigned)(mine & 0xFFFFFFFFu);
      unsigned lab = fi % NCLS;
      unsigned a = fi / NCLS;
      p.out[NTOT + g] = (float)lab;
      for (int j = 0; j < 4; ++j) {
        float bv = box[a*4 + j];
        float nb = bv / img;
        nb = fminf(fmaxf(nb, 0.0f), 1.0f);
        p.out[2*NTOT + g*4 + j] = nb;
        p.slot_box[g*4 + j] = bv;
      }
      p.slot_bits[g] = bits;
      p.slot_label[g] = lab;
    }
  }
  // defensive fill (m < kL should never happen; out is poisoned so must write)
  for (int r = m + tid; r < kL; r += 1024) {
    int g = base + r;
    p.out[NTOT + g] = 0.0f;
    for (int j = 0; j < 4; ++j) { p.out[2*NTOT + g*4 + j] = 0.0f; p.slot_box[g*4+j] = 0.0f; }
    p.slot_bits[g] = 0u; p.slot_label[g] = 0u;
  }
}

// Per-class NMS (cross-class IoU is 0 due to CLASS_OFFSET=2 and boxes in [0,1])
__global__ __launch_bounds__(64) void k_nms(Params p) {
  int c = blockIdx.x, tid = threadIdx.x;
  __shared__ unsigned mcnt;
  __shared__ unsigned long long key[NMS_CAP];
  __shared__ unsigned long long skey[NMS_CAP];
  __shared__ float bx[NMS_CAP*4];
  __shared__ int keep[NMS_CAP];
  if (tid == 0) mcnt = 0u;
  __syncthreads();
  for (int g = tid; g < NTOT; g += 64) {
    if (p.slot_label[g] == (unsigned)c) {
      unsigned pos = atomicAdd(&mcnt, 1u);
      if (pos < NMS_CAP)
        key[pos] = ((unsigned long long)p.slot_bits[g] << 32)
                 | (unsigned long long)(0xFFFFFFFFu - (unsigned)g);
    }
  }
  __syncthreads();
  int m = (mcnt < NMS_CAP) ? (int)mcnt : NMS_CAP;
  if (m == 0) return;
  // rank-sort descending into skey
  for (int i = tid; i < m; i += 64) {
    unsigned long long mine = key[i];
    int rank = 0;
    for (int j = 0; j < m; ++j) rank += (key[j] > mine) ? 1 : 0;
    skey[rank] = mine;
  }
  __syncthreads();
  float off = 2.0f * (float)c;
  for (int j = tid; j < m; j += 64) {
    unsigned long long kk = skey[j];
    unsigned g = 0xFFFFFFFFu - (unsigned)(kk & 0xFFFFFFFFu);
    for (int q = 0; q < 4; ++q) bx[j*4+q] = p.slot_box[g*4+q] + off;
    float s = __uint_as_float((unsigned)(kk >> 32));
    keep[j] = (s > 0.05f) ? 1 : 0;
  }
  __syncthreads();
  for (int i = 0; i + 1 < m; ++i) {
    if (keep[i]) {
      float ax1 = bx[i*4+0], ay1 = bx[i*4+1], ax2 = bx[i*4+2], ay2 = bx[i*4+3];
      for (int j = i + 1 + tid; j < m; j += 64) {
        if (keep[j]) {
          if (iou_ref(ax1,ay1,ax2,ay2, bx[j*4+0],bx[j*4+1],bx[j*4+2],bx[j*4+3]) > 0.6f)
            keep[j] = 0;
        }
      }
    }
    __syncthreads();
  }
  for (int j = tid; j < m; j += 64) {
    unsigned long long kk = skey[j];
    unsigned g = 0xFFFFFFFFu - (unsigned)(kk & 0xFFFFFFFFu);
    float s = __uint_as_float((unsigned)(kk >> 32));
    int kp = keep[j];
    p.out[g] = kp ? s : 0.0f;
    p.out[6*NTOT + g] = kp ? 1.0f : 0.0f;
  }
}

extern "C" void kernel_launch(void* const* d_in, const int* in_sizes, int n_in,
                              void* d_out, int out_size, void* d_ws, size_t ws_size,
                              hipStream_t stream) {
  Params p;
  p.cls0 = (const float*)d_in[0];  p.ctn0 = (const float*)d_in[1];  p.box0 = (const float*)d_in[2];
  p.cls1 = (const float*)d_in[3];  p.ctn1 = (const float*)d_in[4];  p.box1 = (const float*)d_in[5];
  p.cls2 = (const float*)d_in[6];  p.ctn2 = (const float*)d_in[7];  p.box2 = (const float*)d_in[8];
  p.cls3 = (const float*)d_in[9];  p.ctn3 = (const float*)d_in[10]; p.box3 = (const float*)d_in[11];
  p.cls4 = (const float*)d_in[12]; p.ctn4 = (const float*)d_in[13]; p.box4 = (const float*)d_in[14];
  p.img  = (const int*)d_in[15];

  char* w = (char*)d_ws;
  p.cand = (unsigned long long*)w;  w += (size_t)5*CAND_CAP*8;
  p.blockhist = (unsigned*)w;       w += (size_t)NBLK*NB*4;
  p.cnt  = (unsigned*)w;            w += 5*4;
  p.thr  = (unsigned*)w;            w += 5*4;
  p.slot_bits  = (unsigned*)w;      w += NTOT*4;
  p.slot_label = (unsigned*)w;      w += NTOT*4;
  p.slot_box   = (float*)w;         w += NTOT*4*4;
  p.out = (float*)d_out;

  hipLaunchKernelGGL(k_hist,     dim3(NBLK),              dim3(256),  0, stream, p);
  hipLaunchKernelGGL(k_thresh,   dim3(5),                 dim3(256),  0, stream, p);
  hipLaunchKernelGGL(k_gather,   dim3((TOTAL_E+255)/256), dim3(256),  0, stream, p);
  hipLaunchKernelGGL(k_sort_out, dim3(5),                 dim3(1024), 0, stream, p);
  hipLaunchKernelGGL(k_nms,      dim3(80),                dim3(64),   0, stream, p);
}

// Round 3
// 282.324 us; speedup vs baseline: 3.8205x; 1.7468x over previous
//
#include <hip/hip_runtime.h>
#include <math.h>

#pragma clang fp contract(off)

#define NCLS 80
#define NTOT 3800
#define CAND_CAP 4096
#define NMS_CAP 1024
#define TOTAL_E 4264000
#define C1 3200000
#define C2 4000000
#define C3 4200000
#define C4 4251200
// histogram over score float-bits in [0.25, 1.0): 1024 bins of 2^14 ULP
#define BIN_LO 0x3E800000u
#define NB 1024
#define BSHIFT 14
// k_score blocking: quads (4 elements) per block
#define QPB 1024
#define NBLK 1044
#define QTOT 1066000

__constant__ int d_BSQ[6]  = {0, 782, 978, 1027, 1040, 1044};   // block ranges per level
__constant__ int d_QL[5]   = {800000, 200000, 50000, 12800, 3200}; // quads per level
__constant__ int d_EOFF[5] = {0, 3200000, 4000000, 4200000, 4251200}; // element offset
__constant__ int d_QB[6]   = {0, 800000, 1000000, 1050000, 1062800, 1066000}; // quad cumsum

struct Params {
  const float *cls0,*cls1,*cls2,*cls3,*cls4;
  const float *ctn0,*ctn1,*ctn2,*ctn3,*ctn4;
  const float *box0,*box1,*box2,*box3,*box4;
  const int* img;
  unsigned* score_bits;      // TOTAL_E (stored path only)
  unsigned short* blockhist; // NBLK * NB
  unsigned* tot;             // 5 * NB
  unsigned* cnt;             // 5
  unsigned* thr;             // 5
  unsigned long long* cand;  // 5*CAND_CAP
  unsigned* slot_bits;       // NTOT
  unsigned* slot_label;      // NTOT
  float* slot_box;           // NTOT*4 (raw boxes)
  float* out;                // 26600 floats
};

// --- score: emulate f32 pipeline with correctly-rounded expf (f64 exp -> f32)
__device__ __forceinline__ float sigmoid_ref(float x) {
  float e = (float)exp(-(double)x);
  return 1.0f / (1.0f + e);
}
__device__ __forceinline__ float score_ref(float c, float t) {
  return sqrtf(sigmoid_ref(c) * sigmoid_ref(t));
}

__device__ __forceinline__ float iou_ref(float ax1,float ay1,float ax2,float ay2,
                                         float bx1,float by1,float bx2,float by2) {
  float areaA = fmaxf(ax2-ax1,0.0f) * fmaxf(ay2-ay1,0.0f);
  float areaB = fmaxf(bx2-bx1,0.0f) * fmaxf(by2-by1,0.0f);
  float ix1 = fmaxf(ax1,bx1), iy1 = fmaxf(ay1,by1);
  float ix2 = fminf(ax2,bx2), iy2 = fminf(ay2,by2);
  float inter = fmaxf(ix2-ix1,0.0f) * fmaxf(iy2-iy1,0.0f);
  float uni = areaA + areaB - inter;
  return inter / fmaxf(uni, 1e-9f);
}

__device__ __forceinline__ void decode(int idx, const Params& p,
                                       int& l, int& f, const float*& cls, const float*& ctn) {
  if (idx < C1)      { l=0; f=idx;     cls=p.cls0; ctn=p.ctn0; }
  else if (idx < C2) { l=1; f=idx-C1;  cls=p.cls1; ctn=p.ctn1; }
  else if (idx < C3) { l=2; f=idx-C2;  cls=p.cls2; ctn=p.ctn2; }
  else if (idx < C4) { l=3; f=idx-C3;  cls=p.cls3; ctn=p.ctn3; }
  else               { l=4; f=idx-C4;  cls=p.cls4; ctn=p.ctn4; }
}

// Pass 1: score all elements (float4 cls, shared ctn sigmoid per quad),
// optionally store bits, build per-block LDS hist -> u16 global rows.
__global__ __launch_bounds__(256) void k_score(Params p, int store) {
  int b = blockIdx.x, tid = threadIdx.x;
  __shared__ unsigned h[NB];
  for (int i = tid; i < NB; i += 256) h[i] = 0u;
  __syncthreads();
  int l = 0;
  while (b >= d_BSQ[l+1]) ++l;
  int cb = b - d_BSQ[l];
  int q0 = cb * QPB;
  int nq = d_QL[l] - q0; if (nq > QPB) nq = QPB;
  const float* cls = (l==0)?p.cls0:(l==1)?p.cls1:(l==2)?p.cls2:(l==3)?p.cls3:p.cls4;
  const float* ctn = (l==0)?p.ctn0:(l==1)?p.ctn1:(l==2)?p.ctn2:(l==3)?p.ctn3:p.ctn4;
  unsigned* sb = p.score_bits + d_EOFF[l];
  for (int i = tid; i < nq; i += 256) {
    int q = q0 + i;
    float4 c4 = ((const float4*)cls)[q];
    float st = sigmoid_ref(ctn[q / 20]);   // anchor = (4q)/80
    float s0 = sqrtf(sigmoid_ref(c4.x) * st);
    float s1 = sqrtf(sigmoid_ref(c4.y) * st);
    float s2 = sqrtf(sigmoid_ref(c4.z) * st);
    float s3 = sqrtf(sigmoid_ref(c4.w) * st);
    unsigned b0 = __float_as_uint(s0), b1 = __float_as_uint(s1);
    unsigned b2 = __float_as_uint(s2), b3 = __float_as_uint(s3);
    if (store) ((uint4*)sb)[q] = make_uint4(b0,b1,b2,b3);
    if (b0 >= BIN_LO) atomicAdd(&h[(b0 - BIN_LO) >> BSHIFT], 1u);
    if (b1 >= BIN_LO) atomicAdd(&h[(b1 - BIN_LO) >> BSHIFT], 1u);
    if (b2 >= BIN_LO) atomicAdd(&h[(b2 - BIN_LO) >> BSHIFT], 1u);
    if (b3 >= BIN_LO) atomicAdd(&h[(b3 - BIN_LO) >> BSHIFT], 1u);
  }
  __syncthreads();
  unsigned short* out = p.blockhist + (size_t)b * NB;
  for (int i = tid; i < NB; i += 256) out[i] = (unsigned short)h[i];
}

// Parallel reduce: 5 levels x 16 chunks of 64 bins; 4 row-lanes x 4-acc unroll
__global__ __launch_bounds__(256) void k_reduce(Params p) {
  int l = blockIdx.x >> 4, c = blockIdx.x & 15, tid = threadIdx.x;
  int b0 = d_BSQ[l], rows = d_BSQ[l+1] - b0;
  int bin = c*64 + (tid & 63);
  int rlane = tid >> 6;  // 0..3
  const unsigned short* bh = p.blockhist + (size_t)b0 * NB + bin;
  unsigned a0=0,a1=0,a2=0,a3=0;
  int r = rlane;
  for (; r + 12 < rows; r += 16) {
    a0 += bh[(size_t)r * NB];
    a1 += bh[(size_t)(r+4) * NB];
    a2 += bh[(size_t)(r+8) * NB];
    a3 += bh[(size_t)(r+12) * NB];
  }
  for (; r < rows; r += 4) a0 += bh[(size_t)r * NB];
  unsigned acc = a0+a1+a2+a3;
  __shared__ unsigned red[256];
  red[tid] = acc;
  __syncthreads();
  if (tid < 64)
    p.tot[l*NB + c*64 + tid] = red[tid] + red[tid+64] + red[tid+128] + red[tid+192];
}

// Scan per-level totals for k-th threshold bin
__global__ __launch_bounds__(256) void k_scan(Params p) {
  int l = blockIdx.x, tid = threadIdx.x;
  __shared__ unsigned tot[NB];
  __shared__ unsigned csum[256];
  for (int j = 0; j < NB/256; ++j) tot[tid + 256*j] = p.tot[l*NB + tid + 256*j];
  __syncthreads();
  {
    unsigned s = 0;
    for (int j = 0; j < 4; ++j) s += tot[tid*4 + j];
    csum[tid] = s;
  }
  __syncthreads();
  if (tid == 0) {
    const int KL[5] = {1000,1000,1000,640,160};
    unsigned k = (unsigned)KL[l];
    unsigned cum = 0; int chunk = 255;
    for (; chunk > 0; --chunk) {
      if (cum + csum[chunk] >= k) break;
      cum += csum[chunk];
    }
    unsigned t = BIN_LO;
    unsigned c2 = cum;
    for (int i = 3; i >= 0; --i) {
      int bin = chunk*4 + i;
      c2 += tot[bin];
      if (c2 >= k) { t = BIN_LO + ((unsigned)bin << BSHIFT); break; }
    }
    p.thr[l] = t;
    p.cnt[l] = 0u;
  }
}

// Pass 2a (stored): reload bits, push candidates
__global__ __launch_bounds__(256) void k_gather_stored(Params p) {
  int g = blockIdx.x*256 + threadIdx.x;
  if (g >= QTOT) return;
  int l = 0;
  while (g >= d_QB[l+1]) ++l;
  int f = 4 * (g - d_QB[l]);
  uint4 v = ((const uint4*)p.score_bits)[g];
  unsigned t = p.thr[l];
  unsigned bits[4] = {v.x, v.y, v.z, v.w};
  #pragma unroll
  for (int j = 0; j < 4; ++j) {
    if (bits[j] >= t) {
      unsigned pos = atomicAdd(&p.cnt[l], 1u);
      if (pos < CAND_CAP)
        p.cand[l*CAND_CAP + pos] =
          ((unsigned long long)bits[j] << 32) | (unsigned long long)(0xFFFFFFFFu - (unsigned)(f + j));
    }
  }
}

// Pass 2b (fallback): recompute scores
__global__ __launch_bounds__(256) void k_gather_recompute(Params p) {
  int idx = blockIdx.x*256 + threadIdx.x;
  if (idx >= TOTAL_E) return;
  int l, f; const float *cls, *ctn;
  decode(idx, p, l, f, cls, ctn);
  float s = score_ref(cls[f], ctn[f / NCLS]);
  unsigned bits = __float_as_uint(s);
  if (bits >= p.thr[l]) {
    unsigned pos = atomicAdd(&p.cnt[l], 1u);
    if (pos < CAND_CAP)
      p.cand[l*CAND_CAP + pos] =
        ((unsigned long long)bits << 32) | (unsigned long long)(0xFFFFFFFFu - (unsigned)f);
  }
}

// Rank-sort + emit labels/normalized boxes
__global__ __launch_bounds__(1024) void k_sort_out(Params p) {
  int l = blockIdx.x, tid = threadIdx.x;
  __shared__ unsigned long long key[CAND_CAP];
  unsigned mc = p.cnt[l];
  int m = (mc < CAND_CAP) ? (int)mc : CAND_CAP;
  const unsigned long long* cd = p.cand + (size_t)l*CAND_CAP;
  for (int i = tid; i < m; i += 1024) key[i] = cd[i];
  __syncthreads();
  const int KL[5] = {1000,1000,1000,640,160};
  const int OB[5] = {0,1000,2000,3000,3640};
  const float* box = (l==0)?p.box0:(l==1)?p.box1:(l==2)?p.box2:(l==3)?p.box3:p.box4;
  int kL = KL[l], base = OB[l];
  float img = (float)(*p.img);
  for (int i = tid; i < m; i += 1024) {
    unsigned long long mine = key[i];
    int rank = 0;
    for (int j = 0; j < m; ++j) rank += (key[j] > mine) ? 1 : 0;
    if (rank < kL) {
      int g = base + rank;
      unsigned bits = (unsigned)(mine >> 32);
      unsigned fi = 0xFFFFFFFFu - (unsigned)(mine & 0xFFFFFFFFu);
      unsigned lab = fi % NCLS;
      unsigned a = fi / NCLS;
      p.out[NTOT + g] = (float)lab;
      for (int j = 0; j < 4; ++j) {
        float bv = box[a*4 + j];
        float nb = bv / img;
        nb = fminf(fmaxf(nb, 0.0f), 1.0f);
        p.out[2*NTOT + g*4 + j] = nb;
        p.slot_box[g*4 + j] = bv;
      }
      p.slot_bits[g] = bits;
      p.slot_label[g] = lab;
    }
  }
  for (int r = m + tid; r < kL; r += 1024) {
    int g = base + r;
    p.out[NTOT + g] = 0.0f;
    for (int j = 0; j < 4; ++j) { p.out[2*NTOT + g*4 + j] = 0.0f; p.slot_box[g*4+j] = 0.0f; }
    p.slot_bits[g] = 0u; p.slot_label[g] = 0u;
  }
}

// Per-class NMS (cross-class IoU is 0 due to CLASS_OFFSET=2 and boxes in [0,1])
__global__ __launch_bounds__(64) void k_nms(Params p) {
  int c = blockIdx.x, tid = threadIdx.x;
  __shared__ unsigned mcnt;
  __shared__ unsigned long long key[NMS_CAP];
  __shared__ unsigned long long skey[NMS_CAP];
  __shared__ float bx[NMS_CAP*4];
  __shared__ int keep[NMS_CAP];
  if (tid == 0) mcnt = 0u;
  __syncthreads();
  for (int g = tid; g < NTOT; g += 64) {
    if (p.slot_label[g] == (unsigned)c) {
      unsigned pos = atomicAdd(&mcnt, 1u);
      if (pos < NMS_CAP)
        key[pos] = ((unsigned long long)p.slot_bits[g] << 32)
                 | (unsigned long long)(0xFFFFFFFFu - (unsigned)g);
    }
  }
  __syncthreads();
  int m = (mcnt < NMS_CAP) ? (int)mcnt : NMS_CAP;
  if (m == 0) return;
  for (int i = tid; i < m; i += 64) {
    unsigned long long mine = key[i];
    int rank = 0;
    for (int j = 0; j < m; ++j) rank += (key[j] > mine) ? 1 : 0;
    skey[rank] = mine;
  }
  __syncthreads();
  float off = 2.0f * (float)c;
  for (int j = tid; j < m; j += 64) {
    unsigned long long kk = skey[j];
    unsigned g = 0xFFFFFFFFu - (unsigned)(kk & 0xFFFFFFFFu);
    for (int q = 0; q < 4; ++q) bx[j*4+q] = p.slot_box[g*4+q] + off;
    float s = __uint_as_float((unsigned)(kk >> 32));
    keep[j] = (s > 0.05f) ? 1 : 0;
  }
  __syncthreads();
  for (int i = 0; i + 1 < m; ++i) {
    if (keep[i]) {
      float ax1 = bx[i*4+0], ay1 = bx[i*4+1], ax2 = bx[i*4+2], ay2 = bx[i*4+3];
      for (int j = i + 1 + tid; j < m; j += 64) {
        if (keep[j]) {
          if (iou_ref(ax1,ay1,ax2,ay2, bx[j*4+0],bx[j*4+1],bx[j*4+2],bx[j*4+3]) > 0.6f)
            keep[j] = 0;
        }
      }
    }
    __syncthreads();
  }
  for (int j = tid; j < m; j += 64) {
    unsigned long long kk = skey[j];
    unsigned g = 0xFFFFFFFFu - (unsigned)(kk & 0xFFFFFFFFu);
    float s = __uint_as_float((unsigned)(kk >> 32));
    int kp = keep[j];
    p.out[g] = kp ? s : 0.0f;
    p.out[6*NTOT + g] = kp ? 1.0f : 0.0f;
  }
}

extern "C" void kernel_launch(void* const* d_in, const int* in_sizes, int n_in,
                              void* d_out, int out_size, void* d_ws, size_t ws_size,
                              hipStream_t stream) {
  Params p;
  p.cls0 = (const float*)d_in[0];  p.ctn0 = (const float*)d_in[1];  p.box0 = (const float*)d_in[2];
  p.cls1 = (const float*)d_in[3];  p.ctn1 = (const float*)d_in[4];  p.box1 = (const float*)d_in[5];
  p.cls2 = (const float*)d_in[6];  p.ctn2 = (const float*)d_in[7];  p.box2 = (const float*)d_in[8];
  p.cls3 = (const float*)d_in[9];  p.ctn3 = (const float*)d_in[10]; p.box3 = (const float*)d_in[11];
  p.cls4 = (const float*)d_in[12]; p.ctn4 = (const float*)d_in[13]; p.box4 = (const float*)d_in[14];
  p.img  = (const int*)d_in[15];

  const size_t SZ_BITS = (size_t)TOTAL_E * 4;            // 17,056,000
  const size_t SZ_CAND = (size_t)5*CAND_CAP*8;           // 163,840
  const size_t SZ_BH   = (size_t)NBLK*NB*2;              // 2,138,112
  const size_t SZ_TOT  = (size_t)5*NB*4;                 // 20,480
  const size_t SZ_MISC = 64 + NTOT*4 + NTOT*4 + NTOT*16; // cnt/thr pad + slots
  const size_t NEED_STORED = SZ_BITS + SZ_CAND + SZ_BH + SZ_TOT + SZ_MISC;
  int store = (ws_size >= NEED_STORED) ? 1 : 0;

  char* w = (char*)d_ws;
  if (store) { p.score_bits = (unsigned*)w; w += SZ_BITS; }
  else       { p.score_bits = (unsigned*)w; }  // unused, aliases cand (never written)
  p.cand = (unsigned long long*)w;  w += SZ_CAND;
  p.blockhist = (unsigned short*)w; w += SZ_BH;
  p.tot  = (unsigned*)w;            w += SZ_TOT;
  p.cnt  = (unsigned*)w;            w += 32;
  p.thr  = (unsigned*)w;            w += 32;
  p.slot_bits  = (unsigned*)w;      w += NTOT*4;
  p.slot_label = (unsigned*)w;      w += NTOT*4;
  p.slot_box   = (float*)w;         w += NTOT*16;
  p.out = (float*)d_out;

  hipLaunchKernelGGL(k_score,  dim3(NBLK), dim3(256),  0, stream, p, store);
  hipLaunchKernelGGL(k_reduce, dim3(80),   dim3(256),  0, stream, p);
  hipLaunchKernelGGL(k_scan,   dim3(5),    dim3(256),  0, stream, p);
  if (store)
    hipLaunchKernelGGL(k_gather_stored, dim3((QTOT+255)/256), dim3(256), 0, stream, p);
  else
    hipLaunchKernelGGL(k_gather_recompute, dim3((TOTAL_E+255)/256), dim3(256), 0, stream, p);
  hipLaunchKernelGGL(k_sort_out, dim3(5),  dim3(1024), 0, stream, p);
  hipLaunchKernelGGL(k_nms,      dim3(80), dim3(64),   0, stream, p);
}

// Round 4
// 230.734 us; speedup vs baseline: 4.6748x; 1.2236x over previous
//
#include <hip/hip_runtime.h>
#include <math.h>

#pragma clang fp contract(off)

#define NCLS 80
#define NTOT 3800
#define CAND_CAP 4096
#define NMS_CAP 1024
// fast-score hist over float-bits [0.5, 1.0): 1024 bins of 2^13 ULP
#define BIN_LO 0x3F000000u
#define NB 1024
#define BSHIFT 13
#define QPB 1024
#define NBLK 1044
#define PBUF_CAP 320

__constant__ int d_BSQ[6]  = {0, 782, 978, 1027, 1040, 1044};
__constant__ int d_QL[5]   = {800000, 200000, 50000, 12800, 3200};
__constant__ int d_EL[5]   = {3200000, 800000, 200000, 51200, 12800};
__constant__ float d_PREHI[5] = {0.86f, 0.82f, 0.78f, 0.74f, 0.74f};
__constant__ int d_SEGCAP[5]  = {64, 96, 192, 320, 320};
__constant__ int d_SEGBASE[5] = {0, 50048, 68864, 78272, 82432};  // entries; total 83712
__constant__ int d_KL[5] = {1000,1000,1000,640,160};
__constant__ int d_OB[5] = {0,1000,2000,3000,3640};

struct Params {
  const float *cls0,*cls1,*cls2,*cls3,*cls4;
  const float *ctn0,*ctn1,*ctn2,*ctn3,*ctn4;
  const float *box0,*box1,*box2,*box3,*box4;
  const int* img;
  unsigned short* blockhist; // NBLK * NB
  unsigned* tot;             // 5 * NB
  unsigned* blkcnt;          // NBLK (raw prefilter counts)
  unsigned long long* pre;   // 83712 entries (per-block segments)
  unsigned* slot_bits;       // NTOT (exact score bits)
  unsigned* slot_label;      // NTOT
  float* slot_box;           // NTOT*4 (raw boxes)
  float* out;                // 26600 floats
};

// fast monotone proxy (deterministic; used identically in hist + filter)
__device__ __forceinline__ float fast_sig(float x) {
  return 1.0f / (1.0f + __expf(-x));
}
__device__ __forceinline__ float fast_score(float c, float t) {
  return sqrtf(fast_sig(c) * fast_sig(t));
}

// exact: emulate ref f32 pipeline with correctly-rounded expf (f64 exp -> f32)
__device__ __forceinline__ float sigmoid_ref(float x) {
  float e = (float)exp(-(double)x);
  return 1.0f / (1.0f + e);
}
__device__ __forceinline__ float score_ref(float c, float t) {
  return sqrtf(sigmoid_ref(c) * sigmoid_ref(t));
}

__device__ __forceinline__ float iou_ref(float ax1,float ay1,float ax2,float ay2,
                                         float bx1,float by1,float bx2,float by2) {
  float areaA = fmaxf(ax2-ax1,0.0f) * fmaxf(ay2-ay1,0.0f);
  float areaB = fmaxf(bx2-bx1,0.0f) * fmaxf(by2-by1,0.0f);
  float ix1 = fmaxf(ax1,bx1), iy1 = fmaxf(ay1,by1);
  float ix2 = fminf(ax2,bx2), iy2 = fminf(ay2,by2);
  float inter = fmaxf(ix2-ix1,0.0f) * fmaxf(iy2-iy1,0.0f);
  float uni = areaA + areaB - inter;
  return inter / fmaxf(uni, 1e-9f);
}

__device__ __forceinline__ const float* cls_of(const Params& p, int l) {
  return (l==0)?p.cls0:(l==1)?p.cls1:(l==2)?p.cls2:(l==3)?p.cls3:p.cls4;
}
__device__ __forceinline__ const float* ctn_of(const Params& p, int l) {
  return (l==0)?p.ctn0:(l==1)?p.ctn1:(l==2)?p.ctn2:(l==3)?p.ctn3:p.ctn4;
}
__device__ __forceinline__ const float* box_of(const Params& p, int l) {
  return (l==0)?p.box0:(l==1)?p.box1:(l==2)?p.box2:(l==3)?p.box3:p.box4;
}

// Pass 1: fast scores -> LDS hist + atomic-free per-block prefilter segments
__global__ __launch_bounds__(256) void k_score(Params p) {
  int b = blockIdx.x, tid = threadIdx.x;
  __shared__ unsigned h[NB];
  __shared__ unsigned long long pbuf[PBUF_CAP];
  __shared__ unsigned pcnt;
  for (int i = tid; i < NB; i += 256) h[i] = 0u;
  if (tid == 0) pcnt = 0u;
  __syncthreads();
  int l = 0;
  while (b >= d_BSQ[l+1]) ++l;
  int cb = b - d_BSQ[l];
  int q0 = cb * QPB;
  int nq = d_QL[l] - q0; if (nq > QPB) nq = QPB;
  const float* cls = cls_of(p, l);
  const float* ctn = ctn_of(p, l);
  float prehi = d_PREHI[l];
  for (int i = tid; i < nq; i += 256) {
    int q = q0 + i;
    float4 c4 = ((const float4*)cls)[q];
    float st = fast_sig(ctn[q / 20]);   // anchor = (4q)/80
    float s[4];
    s[0] = sqrtf(fast_sig(c4.x) * st);
    s[1] = sqrtf(fast_sig(c4.y) * st);
    s[2] = sqrtf(fast_sig(c4.z) * st);
    s[3] = sqrtf(fast_sig(c4.w) * st);
    #pragma unroll
    for (int j = 0; j < 4; ++j) {
      unsigned bits = __float_as_uint(s[j]);
      if (bits >= BIN_LO) atomicAdd(&h[(bits - BIN_LO) >> BSHIFT], 1u);
      if (s[j] >= prehi) {
        unsigned pos = atomicAdd(&pcnt, 1u);   // LDS atomic, rare
        if (pos < PBUF_CAP)
          pbuf[pos] = ((unsigned long long)bits << 32)
                    | (unsigned long long)(0xFFFFFFFFu - (unsigned)(4*q + j));
      }
    }
  }
  __syncthreads();
  unsigned short* hout = p.blockhist + (size_t)b * NB;
  for (int i = tid; i < NB; i += 256) hout[i] = (unsigned short)h[i];
  int cap = d_SEGCAP[l];
  unsigned n = pcnt;
  if (tid == 0) p.blkcnt[b] = n;               // raw; overflow detected downstream
  unsigned nw = n < (unsigned)cap ? n : (unsigned)cap;
  unsigned long long* seg = p.pre + d_SEGBASE[l] + (size_t)cb * cap;
  for (unsigned i = tid; i < nw; i += 256) seg[i] = pbuf[i];
}

// Parallel hist reduce: 5 levels x 16 chunks of 64 bins
__global__ __launch_bounds__(256) void k_reduce(Params p) {
  int l = blockIdx.x >> 4, c = blockIdx.x & 15, tid = threadIdx.x;
  int b0 = d_BSQ[l], rows = d_BSQ[l+1] - b0;
  int bin = c*64 + (tid & 63);
  int rlane = tid >> 6;
  const unsigned short* bh = p.blockhist + (size_t)b0 * NB + bin;
  unsigned a0=0,a1=0,a2=0,a3=0;
  int r = rlane;
  for (; r + 12 < rows; r += 16) {
    a0 += bh[(size_t)r * NB];
    a1 += bh[(size_t)(r+4) * NB];
    a2 += bh[(size_t)(r+8) * NB];
    a3 += bh[(size_t)(r+12) * NB];
  }
  for (; r < rows; r += 4) a0 += bh[(size_t)r * NB];
  __shared__ unsigned red[256];
  red[tid] = a0+a1+a2+a3;
  __syncthreads();
  if (tid < 64)
    p.tot[l*NB + c*64 + tid] = red[tid] + red[tid+64] + red[tid+128] + red[tid+192];
}

// Fused: threshold scan + candidate gather + exact rescore + rank-sort + emit
__global__ __launch_bounds__(1024) void k_sort_out(Params p) {
  int l = blockIdx.x, tid = threadIdx.x;
  __shared__ unsigned long long cand[CAND_CAP];
  __shared__ unsigned tot[NB];
  __shared__ unsigned csum[256];
  __shared__ unsigned ccnt;
  __shared__ int bad;
  __shared__ unsigned thr_s;
  if (tid == 0) { ccnt = 0u; bad = 0; }
  if (tid < NB) tot[tid] = p.tot[l*NB + tid];
  __syncthreads();
  if (tid < 256) {
    unsigned s = 0;
    for (int j = 0; j < 4; ++j) s += tot[tid*4 + j];
    csum[tid] = s;
  }
  __syncthreads();
  if (tid == 0) {
    unsigned k = (unsigned)d_KL[l];
    unsigned cum = 0; int chunk = 255;
    for (; chunk > 0; --chunk) {
      if (cum + csum[chunk] >= k) break;
      cum += csum[chunk];
    }
    int binf = 0; int found = 0;
    unsigned c2 = cum;
    for (int i = 3; i >= 0; --i) {
      int bin = chunk*4 + i;
      c2 += tot[bin];
      if (c2 >= k) { binf = bin; found = 1; break; }
    }
    unsigned t = BIN_LO;
    if (found && binf > 0) t = BIN_LO + ((unsigned)(binf - 1) << BSHIFT); // 1-bin safety
    thr_s = t;
  }
  __syncthreads();
  unsigned thr = thr_s;
  int b0 = d_BSQ[l], nseg = d_BSQ[l+1] - b0, cap = d_SEGCAP[l];
  for (int s = tid; s < nseg; s += 1024)
    if (p.blkcnt[b0 + s] > (unsigned)cap) bad = 1;
  __syncthreads();
  const float* cls = cls_of(p, l);
  const float* ctn = ctn_of(p, l);
  bool fastok = (!bad) && (thr >= __float_as_uint(d_PREHI[l]));
  if (fastok) {
    int total = nseg * cap;
    const unsigned long long* base = p.pre + d_SEGBASE[l];
    for (int i = tid; i < total; i += 1024) {
      int s = i / cap, j = i - s*cap;
      if (j < (int)p.blkcnt[b0 + s]) {
        unsigned long long kk = base[(size_t)s*cap + j];
        if ((unsigned)(kk >> 32) >= thr) {
          unsigned pos = atomicAdd(&ccnt, 1u);
          if (pos < CAND_CAP) cand[pos] = kk;
        }
      }
    }
  } else {
    // slow correct fallback: full rescan of this level with the fast metric
    int ne = d_EL[l];
    for (int e = tid; e < ne; e += 1024) {
      float s = fast_score(cls[e], ctn[e / NCLS]);
      unsigned bits = __float_as_uint(s);
      if (bits >= thr) {
        unsigned pos = atomicAdd(&ccnt, 1u);
        if (pos < CAND_CAP)
          cand[pos] = ((unsigned long long)bits << 32)
                    | (unsigned long long)(0xFFFFFFFFu - (unsigned)e);
      }
    }
  }
  __syncthreads();
  int m = (ccnt < CAND_CAP) ? (int)ccnt : CAND_CAP;
  // exact rescore of survivors (f64 exp path, matches reference bit-for-bit)
  for (int i = tid; i < m; i += 1024) {
    unsigned fi = 0xFFFFFFFFu - (unsigned)(cand[i] & 0xFFFFFFFFu);
    float ex = score_ref(cls[fi], ctn[fi / NCLS]);
    cand[i] = ((unsigned long long)__float_as_uint(ex) << 32)
            | (unsigned long long)(0xFFFFFFFFu - fi);
  }
  __syncthreads();
  int kL = d_KL[l], obase = d_OB[l];
  float img = (float)(*p.img);
  const float* box = box_of(p, l);
  for (int i = tid; i < m; i += 1024) {
    unsigned long long mine = cand[i];
    int rank = 0;
    for (int j = 0; j < m; ++j) rank += (cand[j] > mine) ? 1 : 0;
    if (rank < kL) {
      int g = obase + rank;
      unsigned bits = (unsigned)(mine >> 32);
      unsigned fi = 0xFFFFFFFFu - (unsigned)(mine & 0xFFFFFFFFu);
      unsigned lab = fi % NCLS;
      unsigned a = fi / NCLS;
      p.out[NTOT + g] = (float)lab;
      for (int j = 0; j < 4; ++j) {
        float bv = box[a*4 + j];
        float nb = bv / img;
        nb = fminf(fmaxf(nb, 0.0f), 1.0f);
        p.out[2*NTOT + g*4 + j] = nb;
        p.slot_box[g*4 + j] = bv;
      }
      p.slot_bits[g] = bits;
      p.slot_label[g] = lab;
    }
  }
  for (int r = m + tid; r < kL; r += 1024) {   // defensive (m >= kL in practice)
    int g = obase + r;
    p.out[NTOT + g] = 0.0f;
    for (int j = 0; j < 4; ++j) { p.out[2*NTOT + g*4 + j] = 0.0f; p.slot_box[g*4+j] = 0.0f; }
    p.slot_bits[g] = 0u; p.slot_label[g] = 0u;
  }
}

// Per-class NMS (cross-class IoU is 0 due to CLASS_OFFSET=2, boxes in [0,1])
__global__ __launch_bounds__(64) void k_nms(Params p) {
  int c = blockIdx.x, tid = threadIdx.x;
  __shared__ unsigned mcnt;
  __shared__ unsigned long long key[NMS_CAP];
  __shared__ unsigned long long skey[NMS_CAP];
  __shared__ float bx[NMS_CAP*4];
  __shared__ int keep[NMS_CAP];
  if (tid == 0) mcnt = 0u;
  __syncthreads();
  for (int g = tid; g < NTOT; g += 64) {
    if (p.slot_label[g] == (unsigned)c) {
      unsigned pos = atomicAdd(&mcnt, 1u);
      if (pos < NMS_CAP)
        key[pos] = ((unsigned long long)p.slot_bits[g] << 32)
                 | (unsigned long long)(0xFFFFFFFFu - (unsigned)g);
    }
  }
  __syncthreads();
  int m = (mcnt < NMS_CAP) ? (int)mcnt : NMS_CAP;
  if (m == 0) return;
  for (int i = tid; i < m; i += 64) {
    unsigned long long mine = key[i];
    int rank = 0;
    for (int j = 0; j < m; ++j) rank += (key[j] > mine) ? 1 : 0;
    skey[rank] = mine;
  }
  __syncthreads();
  float off = 2.0f * (float)c;
  for (int j = tid; j < m; j += 64) {
    unsigned long long kk = skey[j];
    unsigned g = 0xFFFFFFFFu - (unsigned)(kk & 0xFFFFFFFFu);
    for (int q = 0; q < 4; ++q) bx[j*4+q] = p.slot_box[g*4+q] + off;
    float s = __uint_as_float((unsigned)(kk >> 32));
    keep[j] = (s > 0.05f) ? 1 : 0;
  }
  __syncthreads();
  for (int i = 0; i + 1 < m; ++i) {
    if (keep[i]) {
      float ax1 = bx[i*4+0], ay1 = bx[i*4+1], ax2 = bx[i*4+2], ay2 = bx[i*4+3];
      for (int j = i + 1 + tid; j < m; j += 64) {
        if (keep[j]) {
          if (iou_ref(ax1,ay1,ax2,ay2, bx[j*4+0],bx[j*4+1],bx[j*4+2],bx[j*4+3]) > 0.6f)
            keep[j] = 0;
        }
      }
    }
    __syncthreads();
  }
  for (int j = tid; j < m; j += 64) {
    unsigned long long kk = skey[j];
    unsigned g = 0xFFFFFFFFu - (unsigned)(kk & 0xFFFFFFFFu);
    float s = __uint_as_float((unsigned)(kk >> 32));
    int kp = keep[j];
    p.out[g] = kp ? s : 0.0f;
    p.out[6*NTOT + g] = kp ? 1.0f : 0.0f;
  }
}

extern "C" void kernel_launch(void* const* d_in, const int* in_sizes, int n_in,
                              void* d_out, int out_size, void* d_ws, size_t ws_size,
                              hipStream_t stream) {
  Params p;
  p.cls0 = (const float*)d_in[0];  p.ctn0 = (const float*)d_in[1];  p.box0 = (const float*)d_in[2];
  p.cls1 = (const float*)d_in[3];  p.ctn1 = (const float*)d_in[4];  p.box1 = (const float*)d_in[5];
  p.cls2 = (const float*)d_in[6];  p.ctn2 = (const float*)d_in[7];  p.box2 = (const float*)d_in[8];
  p.cls3 = (const float*)d_in[9];  p.ctn3 = (const float*)d_in[10]; p.box3 = (const float*)d_in[11];
  p.cls4 = (const float*)d_in[12]; p.ctn4 = (const float*)d_in[13]; p.box4 = (const float*)d_in[14];
  p.img  = (const int*)d_in[15];

  char* w = (char*)d_ws;
  p.pre = (unsigned long long*)w;   w += (size_t)83712 * 8;      // 669,696
  p.blockhist = (unsigned short*)w; w += (size_t)NBLK*NB*2;      // 2,138,112
  p.tot  = (unsigned*)w;            w += (size_t)5*NB*4;         // 20,480
  p.blkcnt = (unsigned*)w;          w += (size_t)NBLK*4 + 64;
  p.slot_bits  = (unsigned*)w;      w += NTOT*4;
  p.slot_label = (unsigned*)w;      w += NTOT*4;
  p.slot_box   = (float*)w;         w += NTOT*16;
  p.out = (float*)d_out;

  hipLaunchKernelGGL(k_score,    dim3(NBLK), dim3(256),  0, stream, p);
  hipLaunchKernelGGL(k_reduce,   dim3(80),   dim3(256),  0, stream, p);
  hipLaunchKernelGGL(k_sort_out, dim3(5),    dim3(1024), 0, stream, p);
  hipLaunchKernelGGL(k_nms,      dim3(80),   dim3(64),   0, stream, p);
}

// Round 5
// 218.505 us; speedup vs baseline: 4.9364x; 1.0560x over previous
//
#include <hip/hip_runtime.h>
#include <math.h>

#pragma clang fp contract(off)

#define NCLS 80
#define NTOT 3800
#define CAND_CAP 4096
#define NMS_CAP 1024
// fast-score hist over float-bits [0.5, 1.0): 1024 bins of 2^13 ULP
#define BIN_LO 0x3F000000u
#define NB 1024
#define BSHIFT 13
#define QPB 1024
#define NBLK 1044
#define PBUF_CAP 320

__constant__ int d_BSQ[6]  = {0, 782, 978, 1027, 1040, 1044};
__constant__ int d_QL[5]   = {800000, 200000, 50000, 12800, 3200};
__constant__ int d_EL[5]   = {3200000, 800000, 200000, 51200, 12800};
__constant__ float d_PREHI[5] = {0.86f, 0.82f, 0.78f, 0.74f, 0.74f};
__constant__ int d_SEGCAP[5]  = {64, 96, 192, 320, 320};
__constant__ int d_SEGBASE[5] = {0, 50048, 68864, 78272, 82432};  // entries; total 83712
__constant__ int d_KL[5] = {1000,1000,1000,640,160};
__constant__ int d_OB[5] = {0,1000,2000,3000,3640};

struct Params {
  const float *cls0,*cls1,*cls2,*cls3,*cls4;
  const float *ctn0,*ctn1,*ctn2,*ctn3,*ctn4;
  const float *box0,*box1,*box2,*box3,*box4;
  const int* img;
  unsigned short* blockhist; // NBLK * NB
  unsigned* tot;             // 5 * NB
  unsigned* blkcnt;          // NBLK (raw prefilter counts)
  unsigned long long* pre;   // 83712 entries (per-block segments)
  unsigned long long* ckey;  // 5*CAND_CAP exact keys (compacted)
  unsigned* ccount;          // 5
  unsigned* slot_bits;       // NTOT (exact score bits)
  unsigned* slot_label;      // NTOT
  float* slot_box;           // NTOT*4 (raw boxes)
  float* out;                // 26600 floats
};

// fast monotone proxy (deterministic; used identically in hist + filter)
__device__ __forceinline__ float fast_sig(float x) {
  return 1.0f / (1.0f + __expf(-x));
}
__device__ __forceinline__ float fast_score(float c, float t) {
  return sqrtf(fast_sig(c) * fast_sig(t));
}

// exact: emulate ref f32 pipeline with correctly-rounded expf (f64 exp -> f32)
__device__ __forceinline__ float sigmoid_ref(float x) {
  float e = (float)exp(-(double)x);
  return 1.0f / (1.0f + e);
}
__device__ __forceinline__ float score_ref(float c, float t) {
  return sqrtf(sigmoid_ref(c) * sigmoid_ref(t));
}

__device__ __forceinline__ float iou_ref(float ax1,float ay1,float ax2,float ay2,
                                         float bx1,float by1,float bx2,float by2) {
  float areaA = fmaxf(ax2-ax1,0.0f) * fmaxf(ay2-ay1,0.0f);
  float areaB = fmaxf(bx2-bx1,0.0f) * fmaxf(by2-by1,0.0f);
  float ix1 = fmaxf(ax1,bx1), iy1 = fmaxf(ay1,by1);
  float ix2 = fminf(ax2,bx2), iy2 = fminf(ay2,by2);
  float inter = fmaxf(ix2-ix1,0.0f) * fmaxf(iy2-iy1,0.0f);
  float uni = areaA + areaB - inter;
  return inter / fmaxf(uni, 1e-9f);
}

__device__ __forceinline__ const float* cls_of(const Params& p, int l) {
  return (l==0)?p.cls0:(l==1)?p.cls1:(l==2)?p.cls2:(l==3)?p.cls3:p.cls4;
}
__device__ __forceinline__ const float* ctn_of(const Params& p, int l) {
  return (l==0)?p.ctn0:(l==1)?p.ctn1:(l==2)?p.ctn2:(l==3)?p.ctn3:p.ctn4;
}
__device__ __forceinline__ const float* box_of(const Params& p, int l) {
  return (l==0)?p.box0:(l==1)?p.box1:(l==2)?p.box2:(l==3)?p.box3:p.box4;
}

// Pass 1: fast scores -> LDS hist + atomic-free per-block prefilter segments
__global__ __launch_bounds__(256) void k_score(Params p) {
  int b = blockIdx.x, tid = threadIdx.x;
  __shared__ unsigned h[NB];
  __shared__ unsigned long long pbuf[PBUF_CAP];
  __shared__ unsigned pcnt;
  for (int i = tid; i < NB; i += 256) h[i] = 0u;
  if (tid == 0) pcnt = 0u;
  __syncthreads();
  int l = 0;
  while (b >= d_BSQ[l+1]) ++l;
  int cb = b - d_BSQ[l];
  int q0 = cb * QPB;
  int nq = d_QL[l] - q0; if (nq > QPB) nq = QPB;
  const float* cls = cls_of(p, l);
  const float* ctn = ctn_of(p, l);
  float prehi = d_PREHI[l];
  for (int i = tid; i < nq; i += 256) {
    int q = q0 + i;
    float4 c4 = ((const float4*)cls)[q];
    float st = fast_sig(ctn[q / 20]);   // anchor = (4q)/80
    float s[4];
    s[0] = sqrtf(fast_sig(c4.x) * st);
    s[1] = sqrtf(fast_sig(c4.y) * st);
    s[2] = sqrtf(fast_sig(c4.z) * st);
    s[3] = sqrtf(fast_sig(c4.w) * st);
    #pragma unroll
    for (int j = 0; j < 4; ++j) {
      unsigned bits = __float_as_uint(s[j]);
      if (bits >= BIN_LO) atomicAdd(&h[(bits - BIN_LO) >> BSHIFT], 1u);
      if (s[j] >= prehi) {
        unsigned pos = atomicAdd(&pcnt, 1u);   // LDS atomic, rare
        if (pos < PBUF_CAP)
          pbuf[pos] = ((unsigned long long)bits << 32)
                    | (unsigned long long)(0xFFFFFFFFu - (unsigned)(4*q + j));
      }
    }
  }
  __syncthreads();
  unsigned short* hout = p.blockhist + (size_t)b * NB;
  for (int i = tid; i < NB; i += 256) hout[i] = (unsigned short)h[i];
  int cap = d_SEGCAP[l];
  unsigned n = pcnt;
  if (tid == 0) p.blkcnt[b] = n;               // raw; overflow detected downstream
  unsigned nw = n < (unsigned)cap ? n : (unsigned)cap;
  unsigned long long* seg = p.pre + d_SEGBASE[l] + (size_t)cb * cap;
  for (unsigned i = tid; i < nw; i += 256) seg[i] = pbuf[i];
}

// Parallel hist reduce: 5 levels x 16 chunks of 64 bins
__global__ __launch_bounds__(256) void k_reduce(Params p) {
  int l = blockIdx.x >> 4, c = blockIdx.x & 15, tid = threadIdx.x;
  int b0 = d_BSQ[l], rows = d_BSQ[l+1] - b0;
  int bin = c*64 + (tid & 63);
  int rlane = tid >> 6;
  const unsigned short* bh = p.blockhist + (size_t)b0 * NB + bin;
  unsigned a0=0,a1=0,a2=0,a3=0;
  int r = rlane;
  for (; r + 12 < rows; r += 16) {
    a0 += bh[(size_t)r * NB];
    a1 += bh[(size_t)(r+4) * NB];
    a2 += bh[(size_t)(r+8) * NB];
    a3 += bh[(size_t)(r+12) * NB];
  }
  for (; r < rows; r += 4) a0 += bh[(size_t)r * NB];
  __shared__ unsigned red[256];
  red[tid] = a0+a1+a2+a3;
  __syncthreads();
  if (tid < 64)
    p.tot[l*NB + c*64 + tid] = red[tid] + red[tid+64] + red[tid+128] + red[tid+192];
}

// Threshold scan + candidate gather + exact rescore -> compacted global keys
__global__ __launch_bounds__(1024) void k_gather(Params p) {
  int l = blockIdx.x, tid = threadIdx.x;
  __shared__ unsigned long long cand[CAND_CAP];
  __shared__ unsigned tot[NB];
  __shared__ unsigned csum[256];
  __shared__ unsigned ccnt;
  __shared__ int bad;
  __shared__ unsigned thr_s;
  if (tid == 0) { ccnt = 0u; bad = 0; }
  if (tid < NB) tot[tid] = p.tot[l*NB + tid];
  __syncthreads();
  if (tid < 256) {
    unsigned s = 0;
    for (int j = 0; j < 4; ++j) s += tot[tid*4 + j];
    csum[tid] = s;
  }
  __syncthreads();
  if (tid == 0) {
    unsigned k = (unsigned)d_KL[l];
    unsigned cum = 0; int chunk = 255;
    for (; chunk > 0; --chunk) {
      if (cum + csum[chunk] >= k) break;
      cum += csum[chunk];
    }
    int binf = 0; int found = 0;
    unsigned c2 = cum;
    for (int i = 3; i >= 0; --i) {
      int bin = chunk*4 + i;
      c2 += tot[bin];
      if (c2 >= k) { binf = bin; found = 1; break; }
    }
    unsigned t = BIN_LO;
    if (found && binf > 0) t = BIN_LO + ((unsigned)(binf - 1) << BSHIFT); // 1-bin safety
    thr_s = t;
  }
  __syncthreads();
  unsigned thr = thr_s;
  int b0 = d_BSQ[l], nseg = d_BSQ[l+1] - b0, cap = d_SEGCAP[l];
  for (int s = tid; s < nseg; s += 1024)
    if (p.blkcnt[b0 + s] > (unsigned)cap) bad = 1;
  __syncthreads();
  const float* cls = cls_of(p, l);
  const float* ctn = ctn_of(p, l);
  bool fastok = (!bad) && (thr >= __float_as_uint(d_PREHI[l]));
  if (fastok) {
    int total = nseg * cap;
    const unsigned long long* base = p.pre + d_SEGBASE[l];
    for (int i = tid; i < total; i += 1024) {
      int s = i / cap, j = i - s*cap;
      if (j < (int)p.blkcnt[b0 + s]) {
        unsigned long long kk = base[(size_t)s*cap + j];
        if ((unsigned)(kk >> 32) >= thr) {
          unsigned pos = atomicAdd(&ccnt, 1u);
          if (pos < CAND_CAP) cand[pos] = kk;
        }
      }
    }
  } else {
    // slow correct fallback: full rescan of this level with the fast metric
    int ne = d_EL[l];
    for (int e = tid; e < ne; e += 1024) {
      float s = fast_score(cls[e], ctn[e / NCLS]);
      unsigned bits = __float_as_uint(s);
      if (bits >= thr) {
        unsigned pos = atomicAdd(&ccnt, 1u);
        if (pos < CAND_CAP)
          cand[pos] = ((unsigned long long)bits << 32)
                    | (unsigned long long)(0xFFFFFFFFu - (unsigned)e);
      }
    }
  }
  __syncthreads();
  int m = (ccnt < CAND_CAP) ? (int)ccnt : CAND_CAP;
  // exact rescore of survivors (f64 exp path, matches reference bit-for-bit)
  unsigned long long* ck = p.ckey + (size_t)l * CAND_CAP;
  for (int i = tid; i < m; i += 1024) {
    unsigned fi = 0xFFFFFFFFu - (unsigned)(cand[i] & 0xFFFFFFFFu);
    float ex = score_ref(cls[fi], ctn[fi / NCLS]);
    ck[i] = ((unsigned long long)__float_as_uint(ex) << 32)
          | (unsigned long long)(0xFFFFFFFFu - fi);
  }
  if (tid == 0) p.ccount[l] = (unsigned)m;
  // defensive fill (m >= kL in practice; out is poisoned so must write if not)
  int kL = d_KL[l], obase = d_OB[l];
  for (int r = m + tid; r < kL; r += 1024) {
    int g = obase + r;
    p.out[NTOT + g] = 0.0f;
    for (int j = 0; j < 4; ++j) { p.out[2*NTOT + g*4 + j] = 0.0f; p.slot_box[g*4+j] = 0.0f; }
    p.slot_bits[g] = 0u; p.slot_label[g] = 0u;
  }
}

// Rank computation spread across CUs: 64 i-slices per level, 1 wave each.
__global__ __launch_bounds__(64) void k_rank(Params p) {
  int bx = blockIdx.x;
  int l = bx >> 6, slice = bx & 63;
  int tid = threadIdx.x;
  __shared__ unsigned long long key[CAND_CAP];
  int m = (int)p.ccount[l];
  int i0 = slice * 64;
  if (i0 >= m) return;
  const unsigned long long* ck = p.ckey + (size_t)l * CAND_CAP;
  for (int j = tid; j < m; j += 64) key[j] = ck[j];
  __syncthreads();
  int i = i0 + tid;
  if (i >= m) return;
  unsigned long long mine = key[i];
  int rank = 0;
  int mm = m & ~7;
  #pragma unroll 1
  for (int j = 0; j < mm; j += 8) {
    rank += (key[j  ] > mine) + (key[j+1] > mine) + (key[j+2] > mine) + (key[j+3] > mine)
          + (key[j+4] > mine) + (key[j+5] > mine) + (key[j+6] > mine) + (key[j+7] > mine);
  }
  for (int j = mm; j < m; ++j) rank += (key[j] > mine) ? 1 : 0;
  if (rank >= d_KL[l]) return;
  int g = d_OB[l] + rank;
  unsigned bits = (unsigned)(mine >> 32);
  unsigned fi = 0xFFFFFFFFu - (unsigned)(mine & 0xFFFFFFFFu);
  unsigned lab = fi % NCLS;
  unsigned a = fi / NCLS;
  float img = (float)(*p.img);
  float4 b4 = ((const float4*)box_of(p, l))[a];
  float4 nb;
  nb.x = fminf(fmaxf(b4.x / img, 0.0f), 1.0f);
  nb.y = fminf(fmaxf(b4.y / img, 0.0f), 1.0f);
  nb.z = fminf(fmaxf(b4.z / img, 0.0f), 1.0f);
  nb.w = fminf(fmaxf(b4.w / img, 0.0f), 1.0f);
  p.out[NTOT + g] = (float)lab;
  ((float4*)(p.out + 2*NTOT))[g] = nb;
  ((float4*)p.slot_box)[g] = b4;
  p.slot_bits[g] = bits;
  p.slot_label[g] = lab;
}

// Per-class NMS (cross-class IoU is 0 due to CLASS_OFFSET=2, boxes in [0,1])
__global__ __launch_bounds__(64) void k_nms(Params p) {
  int c = blockIdx.x, tid = threadIdx.x;
  __shared__ unsigned mcnt;
  __shared__ unsigned long long key[NMS_CAP];
  __shared__ unsigned long long skey[NMS_CAP];
  __shared__ float bx[NMS_CAP*4];
  __shared__ int keep[NMS_CAP];
  if (tid == 0) mcnt = 0u;
  __syncthreads();
  for (int g = tid; g < NTOT; g += 64) {
    if (p.slot_label[g] == (unsigned)c) {
      unsigned pos = atomicAdd(&mcnt, 1u);
      if (pos < NMS_CAP)
        key[pos] = ((unsigned long long)p.slot_bits[g] << 32)
                 | (unsigned long long)(0xFFFFFFFFu - (unsigned)g);
    }
  }
  __syncthreads();
  int m = (mcnt < NMS_CAP) ? (int)mcnt : NMS_CAP;
  if (m == 0) return;
  for (int i = tid; i < m; i += 64) {
    unsigned long long mine = key[i];
    int rank = 0;
    for (int j = 0; j < m; ++j) rank += (key[j] > mine) ? 1 : 0;
    skey[rank] = mine;
  }
  __syncthreads();
  float off = 2.0f * (float)c;
  for (int j = tid; j < m; j += 64) {
    unsigned long long kk = skey[j];
    unsigned g = 0xFFFFFFFFu - (unsigned)(kk & 0xFFFFFFFFu);
    for (int q = 0; q < 4; ++q) bx[j*4+q] = p.slot_box[g*4+q] + off;
    float s = __uint_as_float((unsigned)(kk >> 32));
    keep[j] = (s > 0.05f) ? 1 : 0;
  }
  __syncthreads();
  for (int i = 0; i + 1 < m; ++i) {
    if (keep[i]) {
      float ax1 = bx[i*4+0], ay1 = bx[i*4+1], ax2 = bx[i*4+2], ay2 = bx[i*4+3];
      for (int j = i + 1 + tid; j < m; j += 64) {
        if (keep[j]) {
          if (iou_ref(ax1,ay1,ax2,ay2, bx[j*4+0],bx[j*4+1],bx[j*4+2],bx[j*4+3]) > 0.6f)
            keep[j] = 0;
        }
      }
    }
    __syncthreads();
  }
  for (int j = tid; j < m; j += 64) {
    unsigned long long kk = skey[j];
    unsigned g = 0xFFFFFFFFu - (unsigned)(kk & 0xFFFFFFFFu);
    float s = __uint_as_float((unsigned)(kk >> 32));
    int kp = keep[j];
    p.out[g] = kp ? s : 0.0f;
    p.out[6*NTOT + g] = kp ? 1.0f : 0.0f;
  }
}

extern "C" void kernel_launch(void* const* d_in, const int* in_sizes, int n_in,
                              void* d_out, int out_size, void* d_ws, size_t ws_size,
                              hipStream_t stream) {
  Params p;
  p.cls0 = (const float*)d_in[0];  p.ctn0 = (const float*)d_in[1];  p.box0 = (const float*)d_in[2];
  p.cls1 = (const float*)d_in[3];  p.ctn1 = (const float*)d_in[4];  p.box1 = (const float*)d_in[5];
  p.cls2 = (const float*)d_in[6];  p.ctn2 = (const float*)d_in[7];  p.box2 = (const float*)d_in[8];
  p.cls3 = (const float*)d_in[9];  p.ctn3 = (const float*)d_in[10]; p.box3 = (const float*)d_in[11];
  p.cls4 = (const float*)d_in[12]; p.ctn4 = (const float*)d_in[13]; p.box4 = (const float*)d_in[14];
  p.img  = (const int*)d_in[15];

  char* w = (char*)d_ws;
  p.pre = (unsigned long long*)w;   w += (size_t)83712 * 8;        // 669,696
  p.blockhist = (unsigned short*)w; w += (size_t)NBLK*NB*2;        // 2,138,112
  p.tot  = (unsigned*)w;            w += (size_t)5*NB*4;           // 20,480
  p.blkcnt = (unsigned*)w;          w += (size_t)NBLK*4 + 64;      // 4,240
  p.ckey = (unsigned long long*)w;  w += (size_t)5*CAND_CAP*8;     // 163,840
  p.ccount = (unsigned*)w;          w += 32;
  p.slot_bits  = (unsigned*)w;      w += NTOT*4;
  p.slot_label = (unsigned*)w;      w += NTOT*4;
  p.slot_box   = (float*)w;         w += NTOT*16;
  p.out = (float*)d_out;

  hipLaunchKernelGGL(k_score,  dim3(NBLK),  dim3(256),  0, stream, p);
  hipLaunchKernelGGL(k_reduce, dim3(80),    dim3(256),  0, stream, p);
  hipLaunchKernelGGL(k_gather, dim3(5),     dim3(1024), 0, stream, p);
  hipLaunchKernelGGL(k_rank,   dim3(5*64),  dim3(64),   0, stream, p);
  hipLaunchKernelGGL(k_nms,    dim3(80),    dim3(64),   0, stream, p);
}

// Round 6
// 209.473 us; speedup vs baseline: 5.1492x; 1.0431x over previous
//
#include <hip/hip_runtime.h>
#include <math.h>

#pragma clang fp contract(off)

typedef unsigned long long ull;

#define NCLS 80
#define NTOT 3800
#define CAND_CAP 4096
#define NMS_CAP 1024
#define CLS_CAP 128
// fast-score hist over float-bits [0.5, 1.0): 1024 bins of 2^13 ULP
#define BIN_LO 0x3F000000u
#define NB 1024
#define BSHIFT 13
#define QPB 1024
#define NBLK 1044
#define SEGCAP 320
#define ZWORDS 6496   // tot(5120) + ccount(80) + clscnt(1280) + lvlbad(16)

__constant__ int d_BSQ[6]  = {0, 782, 978, 1027, 1040, 1044};
__constant__ int d_QL[5]   = {800000, 200000, 50000, 12800, 3200};
__constant__ int d_EL[5]   = {3200000, 800000, 200000, 51200, 12800};
__constant__ float d_PREHI[5] = {0.86f, 0.82f, 0.78f, 0.74f, 0.74f};
__constant__ int d_KL[5] = {1000,1000,1000,640,160};
__constant__ int d_OB[5] = {0,1000,2000,3000,3640};

struct Params {
  const float *cls0,*cls1,*cls2,*cls3,*cls4;
  const float *ctn0,*ctn1,*ctn2,*ctn3,*ctn4;
  const float *box0,*box1,*box2,*box3,*box4;
  const int* img;
  ull* pre;                  // NBLK * SEGCAP
  unsigned* tot;             // 5*NB  (zero region starts here)
  unsigned* ccount;          // 5 x stride16 words
  unsigned* clscnt;          // 80 x stride16 words
  unsigned* lvlbad;          // 5 (padded 16)
  unsigned* blkcnt;          // NBLK
  ull* ckey;                 // 5*CAND_CAP exact keys (compacted)
  ull* clskey;               // 80*CLS_CAP
  unsigned* slot_bits;       // NTOT
  unsigned* slot_label;      // NTOT
  float* slot_box;           // NTOT*4
  float* out;                // 26600 floats
};

__device__ __forceinline__ float fast_sig(float x) {
  return 1.0f / (1.0f + __expf(-x));
}
__device__ __forceinline__ float fast_score(float c, float t) {
  return sqrtf(fast_sig(c) * fast_sig(t));
}
// exact: emulate ref f32 pipeline with correctly-rounded expf (f64 exp -> f32)
__device__ __forceinline__ float sigmoid_ref(float x) {
  float e = (float)exp(-(double)x);
  return 1.0f / (1.0f + e);
}
__device__ __forceinline__ float score_ref(float c, float t) {
  return sqrtf(sigmoid_ref(c) * sigmoid_ref(t));
}
__device__ __forceinline__ float iou_ref(float ax1,float ay1,float ax2,float ay2,
                                         float bx1,float by1,float bx2,float by2) {
  float areaA = fmaxf(ax2-ax1,0.0f) * fmaxf(ay2-ay1,0.0f);
  float areaB = fmaxf(bx2-bx1,0.0f) * fmaxf(by2-by1,0.0f);
  float ix1 = fmaxf(ax1,bx1), iy1 = fmaxf(ay1,by1);
  float ix2 = fminf(ax2,bx2), iy2 = fminf(ay2,by2);
  float inter = fmaxf(ix2-ix1,0.0f) * fmaxf(iy2-iy1,0.0f);
  float uni = areaA + areaB - inter;
  return inter / fmaxf(uni, 1e-9f);
}
__device__ __forceinline__ const float* cls_of(const Params& p, int l) {
  return (l==0)?p.cls0:(l==1)?p.cls1:(l==2)?p.cls2:(l==3)?p.cls3:p.cls4;
}
__device__ __forceinline__ const float* ctn_of(const Params& p, int l) {
  return (l==0)?p.ctn0:(l==1)?p.ctn1:(l==2)?p.ctn2:(l==3)?p.ctn3:p.ctn4;
}
__device__ __forceinline__ const float* box_of(const Params& p, int l) {
  return (l==0)?p.box0:(l==1)?p.box1:(l==2)?p.box2:(l==3)?p.box3:p.box4;
}

__global__ __launch_bounds__(256) void k_zero(unsigned* z) {
  for (int i = blockIdx.x*256 + threadIdx.x; i < ZWORDS; i += 256) z[i] = 0u;
}

// Pass 1: fast scores -> LDS hist (merged via global atomics on nonzero bins)
//         + atomic-free per-block prefilter segments
__global__ __launch_bounds__(256) void k_score(Params p) {
  int b = blockIdx.x, tid = threadIdx.x;
  __shared__ unsigned h[NB];
  __shared__ ull pbuf[SEGCAP];
  __shared__ unsigned pcnt;
  for (int i = tid; i < NB; i += 256) h[i] = 0u;
  if (tid == 0) pcnt = 0u;
  __syncthreads();
  int l = 0;
  while (b >= d_BSQ[l+1]) ++l;
  int cb = b - d_BSQ[l];
  int q0 = cb * QPB;
  int nq = d_QL[l] - q0; if (nq > QPB) nq = QPB;
  const float* cls = cls_of(p, l);
  const float* ctn = ctn_of(p, l);
  float prehi = d_PREHI[l];
  for (int i = tid; i < nq; i += 256) {
    int q = q0 + i;
    float4 c4 = ((const float4*)cls)[q];
    float st = fast_sig(ctn[q / 20]);   // anchor = (4q)/80
    float s[4];
    s[0] = sqrtf(fast_sig(c4.x) * st);
    s[1] = sqrtf(fast_sig(c4.y) * st);
    s[2] = sqrtf(fast_sig(c4.z) * st);
    s[3] = sqrtf(fast_sig(c4.w) * st);
    #pragma unroll
    for (int j = 0; j < 4; ++j) {
      unsigned bits = __float_as_uint(s[j]);
      if (bits >= BIN_LO) atomicAdd(&h[(bits - BIN_LO) >> BSHIFT], 1u);
      if (s[j] >= prehi) {
        unsigned pos = atomicAdd(&pcnt, 1u);
        if (pos < SEGCAP)
          pbuf[pos] = ((ull)bits << 32) | (ull)(0xFFFFFFFFu - (unsigned)(4*q + j));
      }
    }
  }
  __syncthreads();
  // merge nonzero bins into global per-level hist
  unsigned* tl = p.tot + l*NB;
  for (int i = tid; i < NB; i += 256) {
    unsigned v = h[i];
    if (v) atomicAdd(&tl[i], v);
  }
  unsigned n = pcnt;
  if (tid == 0) {
    p.blkcnt[b] = n;
    if (n > SEGCAP) p.lvlbad[l] = 1u;
  }
  unsigned nw = n < SEGCAP ? n : SEGCAP;
  ull* seg = p.pre + (size_t)b * SEGCAP;
  for (unsigned i = tid; i < nw; i += 256) seg[i] = pbuf[i];
}

// 40 blocks (5 levels x 8 slices): parallel threshold scan + segment gather
// + exact f64 rescore -> compacted global keys (1 global atomic per block)
__global__ __launch_bounds__(256) void k_gather(Params p) {
  int bx = blockIdx.x;
  int l = bx >> 3, slice = bx & 7;
  int tid = threadIdx.x;
  __shared__ unsigned sfx[NB];
  __shared__ ull cbuf[CAND_CAP];
  __shared__ unsigned pcnt;
  __shared__ unsigned thr_sh;
  __shared__ unsigned base_sh;
  if (tid == 0) { pcnt = 0u; thr_sh = BIN_LO; }
  for (int j = tid; j < NB; j += 256) sfx[j] = p.tot[l*NB + j];
  __syncthreads();
  // suffix-sum via staged Hillis-Steele (10 steps)
  for (int off = 1; off < NB; off <<= 1) {
    unsigned v[4];
    #pragma unroll
    for (int j = 0; j < 4; ++j) {
      int idx = tid + j*256;
      unsigned add = (idx + off < NB) ? sfx[idx + off] : 0u;
      v[j] = sfx[idx] + add;
    }
    __syncthreads();
    #pragma unroll
    for (int j = 0; j < 4; ++j) sfx[tid + j*256] = v[j];
    __syncthreads();
  }
  unsigned k = (unsigned)d_KL[l];
  #pragma unroll
  for (int j = 0; j < 4; ++j) {
    int b = tid + j*256;
    unsigned s0 = sfx[b];
    unsigned s1 = (b + 1 < NB) ? sfx[b+1] : 0u;
    if (s0 >= k && (b == NB-1 || s1 < k)) {
      // largest bin with suffix >= k; lower by 1 bin for fast-vs-exact safety
      thr_sh = (b > 0) ? (BIN_LO + ((unsigned)(b-1) << BSHIFT)) : BIN_LO;
    }
  }
  __syncthreads();
  unsigned thr = thr_sh;
  const float* cls = cls_of(p, l);
  const float* ctn = ctn_of(p, l);
  bool fallback = (p.lvlbad[l] != 0u) || (thr < __float_as_uint(d_PREHI[l]));
  if (!fallback) {
    int s0b = d_BSQ[l], nseg = d_BSQ[l+1] - s0b;
    int chunk = (nseg + 7) >> 3;
    int sA = slice * chunk, sB = sA + chunk;
    if (sA > nseg) sA = nseg;
    if (sB > nseg) sB = nseg;
    int total = (sB - sA) * SEGCAP;
    const ull* base = p.pre + (size_t)(s0b + sA) * SEGCAP;
    const unsigned* bc = p.blkcnt + s0b + sA;
    for (int i = tid; i < total; i += 256) {
      int s = i / SEGCAP;              // compile-time divisor -> magic mul
      int j = i - s * SEGCAP;
      unsigned cnt = bc[s]; if (cnt > SEGCAP) cnt = SEGCAP;
      if (j < (int)cnt) {
        ull kk = base[(size_t)s * SEGCAP + j];
        if ((unsigned)(kk >> 32) >= thr) {
          unsigned fi = 0xFFFFFFFFu - (unsigned)kk;
          float ex = score_ref(cls[fi], ctn[fi / NCLS]);
          unsigned pos = atomicAdd(&pcnt, 1u);
          if (pos < CAND_CAP)
            cbuf[pos] = ((ull)__float_as_uint(ex) << 32) | (ull)(0xFFFFFFFFu - fi);
        }
      }
    }
  } else {
    // slice-local full rescan with the fast metric, exact rescore on hits
    int ne = d_EL[l];
    int chunk = (ne + 7) >> 3;
    int eA = slice * chunk, eB = eA + chunk;
    if (eA > ne) eA = ne;
    if (eB > ne) eB = ne;
    for (int e = eA + tid; e < eB; e += 256) {
      float s = fast_score(cls[e], ctn[e / NCLS]);
      if (__float_as_uint(s) >= thr) {
        float ex = score_ref(cls[e], ctn[e / NCLS]);
        unsigned pos = atomicAdd(&pcnt, 1u);
        if (pos < CAND_CAP)
          cbuf[pos] = ((ull)__float_as_uint(ex) << 32) | (ull)(0xFFFFFFFFu - (unsigned)e);
      }
    }
  }
  __syncthreads();
  unsigned n = pcnt; if (n > CAND_CAP) n = CAND_CAP;
  if (tid == 0) base_sh = atomicAdd(&p.ccount[l*16], n);
  __syncthreads();
  unsigned bp = base_sh;
  ull* ck = p.ckey + (size_t)l * CAND_CAP;
  for (unsigned i = tid; i < n; i += 256) {
    unsigned d = bp + i;
    if (d < CAND_CAP) ck[d] = cbuf[i];
  }
}

// Rank: 64 i-slices per level, 1 wave each; emits labels/boxes/slots + class lists
__global__ __launch_bounds__(64) void k_rank(Params p) {
  int bx = blockIdx.x;
  int l = bx >> 6, slice = bx & 63;
  int tid = threadIdx.x;
  int m = (int)p.ccount[l*16]; if (m > CAND_CAP) m = CAND_CAP;
  int kL = d_KL[l], obase = d_OB[l];
  int i0 = slice * 64;
  int i = i0 + tid;
  if (i0 >= m) {
    // defensive zero-fill of slots [m, kL) (m >= kL in practice)
    if (i >= m && i < kL) {
      int g = obase + i;
      p.out[g] = 0.0f;
      p.out[NTOT + g] = 0.0f;
      ((float4*)(p.out + 2*NTOT))[g] = make_float4(0,0,0,0);
      p.out[6*NTOT + g] = 0.0f;
      ((float4*)p.slot_box)[g] = make_float4(0,0,0,0);
      p.slot_bits[g] = 0u;
      p.slot_label[g] = 0xFFFFFFFFu;
    }
    return;
  }
  __shared__ ull key[CAND_CAP];
  const ull* ck = p.ckey + (size_t)l * CAND_CAP;
  for (int j = tid; j < m; j += 64) key[j] = ck[j];
  __syncthreads();
  if (i >= m) {
    if (i < kL) {
      int g = obase + i;
      p.out[g] = 0.0f;
      p.out[NTOT + g] = 0.0f;
      ((float4*)(p.out + 2*NTOT))[g] = make_float4(0,0,0,0);
      p.out[6*NTOT + g] = 0.0f;
      ((float4*)p.slot_box)[g] = make_float4(0,0,0,0);
      p.slot_bits[g] = 0u;
      p.slot_label[g] = 0xFFFFFFFFu;
    }
    return;
  }
  ull mine = key[i];
  int rank = 0;
  int mm = m & ~7;
  #pragma unroll 1
  for (int j = 0; j < mm; j += 8) {
    rank += (key[j  ] > mine) + (key[j+1] > mine) + (key[j+2] > mine) + (key[j+3] > mine)
          + (key[j+4] > mine) + (key[j+5] > mine) + (key[j+6] > mine) + (key[j+7] > mine);
  }
  for (int j = mm; j < m; ++j) rank += (key[j] > mine) ? 1 : 0;
  if (rank >= kL) return;
  int g = obase + rank;
  unsigned bits = (unsigned)(mine >> 32);
  unsigned fi = 0xFFFFFFFFu - (unsigned)(mine & 0xFFFFFFFFu);
  unsigned lab = fi % NCLS;
  unsigned a = fi / NCLS;
  float img = (float)(*p.img);
  float4 b4 = ((const float4*)box_of(p, l))[a];
  float4 nb;
  nb.x = fminf(fmaxf(b4.x / img, 0.0f), 1.0f);
  nb.y = fminf(fmaxf(b4.y / img, 0.0f), 1.0f);
  nb.z = fminf(fmaxf(b4.z / img, 0.0f), 1.0f);
  nb.w = fminf(fmaxf(b4.w / img, 0.0f), 1.0f);
  p.out[NTOT + g] = (float)lab;
  ((float4*)(p.out + 2*NTOT))[g] = nb;
  ((float4*)p.slot_box)[g] = b4;
  p.slot_bits[g] = bits;
  p.slot_label[g] = lab;
  unsigned pos = atomicAdd(&p.clscnt[lab*16], 1u);
  if (pos < CLS_CAP)
    p.clskey[lab*CLS_CAP + pos] = ((ull)bits << 32) | (ull)(0xFFFFFFFFu - (unsigned)g);
}

// Per-class NMS. m<=64: single-wave shfl/ballot path (no barriers).
__global__ __launch_bounds__(64) void k_nms(Params p) {
  int c = blockIdx.x, lane = threadIdx.x;
  int mc = (int)p.clscnt[c*16];
  if (mc == 0) return;
  if (mc <= 64) {
    ull kk = (lane < mc) ? p.clskey[c*CLS_CAP + lane] : 0ULL;
    int rank = 0;
    #pragma unroll 1
    for (int j = 0; j < 64; ++j) {
      ull kj = __shfl(kk, j);
      rank += (j < mc && kj > kk) ? 1 : 0;
    }
    __shared__ ull wkey[64];
    if (lane < mc) wkey[rank] = kk;
    __syncthreads();
    ull sk = (lane < mc) ? wkey[lane] : 0ULL;
    unsigned g = 0xFFFFFFFFu - (unsigned)(sk & 0xFFFFFFFFu);
    float s = __uint_as_float((unsigned)(sk >> 32));
    float off = 2.0f * (float)c;
    float x1=0,y1=0,x2=0,y2=0;
    if (lane < mc) {
      float4 b4 = ((const float4*)p.slot_box)[g];
      x1 = b4.x + off; y1 = b4.y + off; x2 = b4.z + off; y2 = b4.w + off;
    }
    ull keepm = __ballot(lane < mc && s > 0.05f);
    for (int i = 0; i + 1 < mc; ++i) {
      if ((keepm >> i) & 1ULL) {
        float ax1 = __shfl(x1, i), ay1 = __shfl(y1, i);
        float ax2 = __shfl(x2, i), ay2 = __shfl(y2, i);
        bool kept = (keepm >> lane) & 1ULL;
        bool sup = kept && (lane > i) && (lane < mc) &&
                   (iou_ref(ax1,ay1,ax2,ay2, x1,y1,x2,y2) > 0.6f);
        keepm &= ~__ballot(sup);
      }
    }
    if (lane < mc) {
      int kp = (int)((keepm >> lane) & 1ULL);
      p.out[g] = kp ? s : 0.0f;
      p.out[6*NTOT + g] = kp ? 1.0f : 0.0f;
    }
    return;
  }
  // LDS path (rare): 64<mc<=128 from clskey; mc>128 rebuild by scanning slots
  __shared__ ull key[NMS_CAP];
  __shared__ ull skey[NMS_CAP];
  __shared__ float bxs[NMS_CAP*4];
  __shared__ int keep[NMS_CAP];
  __shared__ unsigned mcnt_s;
  int m;
  if (mc <= CLS_CAP) {
    for (int j = lane; j < mc; j += 64) key[j] = p.clskey[c*CLS_CAP + j];
    m = mc;
    __syncthreads();
  } else {
    if (lane == 0) mcnt_s = 0u;
    __syncthreads();
    for (int g = lane; g < NTOT; g += 64) {
      if (p.slot_label[g] == (unsigned)c) {
        unsigned pos = atomicAdd(&mcnt_s, 1u);
        if (pos < NMS_CAP)
          key[pos] = ((ull)p.slot_bits[g] << 32) | (ull)(0xFFFFFFFFu - (unsigned)g);
      }
    }
    __syncthreads();
    m = (mcnt_s < NMS_CAP) ? (int)mcnt_s : NMS_CAP;
  }
  for (int i = lane; i < m; i += 64) {
    ull mine = key[i];
    int rank = 0;
    for (int j = 0; j < m; ++j) rank += (key[j] > mine) ? 1 : 0;
    skey[rank] = mine;
  }
  __syncthreads();
  float off = 2.0f * (float)c;
  for (int j = lane; j < m; j += 64) {
    ull kk = skey[j];
    unsigned g = 0xFFFFFFFFu - (unsigned)(kk & 0xFFFFFFFFu);
    for (int q = 0; q < 4; ++q) bxs[j*4+q] = p.slot_box[g*4+q] + off;
    float s = __uint_as_float((unsigned)(kk >> 32));
    keep[j] = (s > 0.05f) ? 1 : 0;
  }
  __syncthreads();
  for (int i = 0; i + 1 < m; ++i) {
    if (keep[i]) {
      float ax1 = bxs[i*4+0], ay1 = bxs[i*4+1], ax2 = bxs[i*4+2], ay2 = bxs[i*4+3];
      for (int j = i + 1 + lane; j < m; j += 64) {
        if (keep[j]) {
          if (iou_ref(ax1,ay1,ax2,ay2, bxs[j*4+0],bxs[j*4+1],bxs[j*4+2],bxs[j*4+3]) > 0.6f)
            keep[j] = 0;
        }
      }
    }
    __syncthreads();
  }
  for (int j = lane; j < m; j += 64) {
    ull kk = skey[j];
    unsigned g = 0xFFFFFFFFu - (unsigned)(kk & 0xFFFFFFFFu);
    float s = __uint_as_float((unsigned)(kk >> 32));
    int kp = keep[j];
    p.out[g] = kp ? s : 0.0f;
    p.out[6*NTOT + g] = kp ? 1.0f : 0.0f;
  }
}

extern "C" void kernel_launch(void* const* d_in, const int* in_sizes, int n_in,
                              void* d_out, int out_size, void* d_ws, size_t ws_size,
                              hipStream_t stream) {
  Params p;
  p.cls0 = (const float*)d_in[0];  p.ctn0 = (const float*)d_in[1];  p.box0 = (const float*)d_in[2];
  p.cls1 = (const float*)d_in[3];  p.ctn1 = (const float*)d_in[4];  p.box1 = (const float*)d_in[5];
  p.cls2 = (const float*)d_in[6];  p.ctn2 = (const float*)d_in[7];  p.box2 = (const float*)d_in[8];
  p.cls3 = (const float*)d_in[9];  p.ctn3 = (const float*)d_in[10]; p.box3 = (const float*)d_in[11];
  p.cls4 = (const float*)d_in[12]; p.ctn4 = (const float*)d_in[13]; p.box4 = (const float*)d_in[14];
  p.img  = (const int*)d_in[15];

  char* w = (char*)d_ws;
  p.pre = (ull*)w;            w += (size_t)NBLK*SEGCAP*8;     // 2,672,640
  // contiguous zero region: tot | ccount | clscnt | lvlbad  (ZWORDS words)
  unsigned* zbase = (unsigned*)w;
  p.tot    = zbase;                       // 5*1024 = 5120 words
  p.ccount = zbase + 5120;                // 5 x stride16 = 80 words
  p.clscnt = zbase + 5120 + 80;           // 80 x stride16 = 1280 words
  p.lvlbad = zbase + 5120 + 80 + 1280;    // 16 words
  w += (size_t)ZWORDS*4;
  p.blkcnt = (unsigned*)w;    w += (size_t)NBLK*4 + 64;
  p.ckey = (ull*)w;           w += (size_t)5*CAND_CAP*8;      // 163,840
  p.clskey = (ull*)w;         w += (size_t)NCLS*CLS_CAP*8;    // 81,920
  p.slot_bits  = (unsigned*)w; w += NTOT*4;
  p.slot_label = (unsigned*)w; w += NTOT*4;
  p.slot_box   = (float*)w;    w += NTOT*16;
  p.out = (float*)d_out;

  hipLaunchKernelGGL(k_zero,   dim3(1),     dim3(256), 0, stream, zbase);
  hipLaunchKernelGGL(k_score,  dim3(NBLK),  dim3(256), 0, stream, p);
  hipLaunchKernelGGL(k_gather, dim3(40),    dim3(256), 0, stream, p);
  hipLaunchKernelGGL(k_rank,   dim3(5*64),  dim3(64),  0, stream, p);
  hipLaunchKernelGGL(k_nms,    dim3(80),    dim3(64),  0, stream, p);
}